// Round 1
// baseline (578.333 us; speedup 1.0000x reference)
//
#include <hip/hip_runtime.h>

// Transformer block on MI355X. bf16 MFMA for all GEMM-shaped work, fp32 stats.
// Layouts: GEMM is C[M,N] = A[M,K] (row-major bf16) x Bt[N,K] (row-major bf16 = B^T).
// MFMA 16x16x32 bf16 fragments (learn_hip verified):
//   A/B frag: [m|n = lane&15][k = (lane>>4)*8 + j], 8 contiguous bf16 per lane.
//   C/D frag: col = lane&15, row = (lane>>4)*4 + reg.

typedef unsigned short u16;
typedef __attribute__((ext_vector_type(8))) short bf16x8;
typedef __attribute__((ext_vector_type(4))) float f32x4;

#define MFMA16(a, b, c) __builtin_amdgcn_mfma_f32_16x16x32_bf16(a, b, c, 0, 0, 0)

__device__ __forceinline__ u16 f2b(float f) {
  unsigned int u = __builtin_bit_cast(unsigned int, f);
  u = (u + 0x7fffu + ((u >> 16) & 1u)) >> 16;
  return (u16)u;
}

// ---------------------------------------------------------------- pack kernels

// elementwise cast fp32 -> bf16, 4 per thread
__global__ __launch_bounds__(256) void castx_kernel(const float* __restrict__ src,
                                                    u16* __restrict__ dst) {
  int i = (blockIdx.x * 256 + threadIdx.x) * 4;
  float4 v = *(const float4*)(src + i);
  dst[i + 0] = f2b(v.x);
  dst[i + 1] = f2b(v.y);
  dst[i + 2] = f2b(v.z);
  dst[i + 3] = f2b(v.w);
}

// tiled transpose+cast: dst[c*R + r] = bf16(src[r*C + c] * scale)
__global__ __launch_bounds__(256) void tcast_kernel(const float* __restrict__ src,
                                                    u16* __restrict__ dst, int R, int C) {
  __shared__ float tile[32][33];
  int tx = threadIdx.x, ty = threadIdx.y;
  int r0 = blockIdx.y * 32, c0 = blockIdx.x * 32;
#pragma unroll
  for (int i = 0; i < 4; ++i)
    tile[ty + i * 8][tx] = src[(size_t)(r0 + ty + i * 8) * C + c0 + tx];
  __syncthreads();
#pragma unroll
  for (int i = 0; i < 4; ++i)
    dst[(size_t)(c0 + ty + i * 8) * R + r0 + tx] = f2b(tile[tx][ty + i * 8]);
}

// per-(proj,head) transpose of [1024 d][64 k] sub-blocks into WqkvT[n=p*1024+h*64+k][d].
// q gets the 1/sqrt(64) score scale folded in.
__global__ __launch_bounds__(256) void tcast_qkv_kernel(const float* __restrict__ wq,
                                                        const float* __restrict__ wk,
                                                        const float* __restrict__ wv,
                                                        u16* __restrict__ dst) {
  __shared__ float tile[32][33];
  int tx = threadIdx.x, ty = threadIdx.y;
  int z = blockIdx.z;
  int p = z >> 4, h = z & 15;
  const float* src = (p == 0 ? wq : (p == 1 ? wk : wv)) + (size_t)h * 1024 * 64;
  float scale = (p == 0) ? 0.125f : 1.0f;
  u16* dbase = dst + (size_t)(p * 1024 + h * 64) * 1024;
  int r0 = blockIdx.y * 32, c0 = blockIdx.x * 32;  // r: d (0..1023), c: k (0..63)
#pragma unroll
  for (int i = 0; i < 4; ++i)
    tile[ty + i * 8][tx] = src[(size_t)(r0 + ty + i * 8) * 64 + c0 + tx];
  __syncthreads();
#pragma unroll
  for (int i = 0; i < 4; ++i)
    dbase[(size_t)(c0 + ty + i * 8) * 1024 + r0 + tx] = f2b(tile[tx][ty + i * 8] * scale);
}

// ---------------------------------------------------------------- GEMM

// MODE 0: C bf16 (no bias)        -> outB
// MODE 1: relu(C + bias) bf16     -> outB
// MODE 2: C + bias + resid fp32   -> outF
#define BM 128
#define BN 128
#define BKG 32
#define LDT 40  // padded LDS stride (bf16 elems), rows stay 16B aligned

template <int MODE>
__global__ __launch_bounds__(256) void gemm_bf16(const u16* __restrict__ A,
                                                 const u16* __restrict__ Bt, int M, int N,
                                                 int K, const float* __restrict__ bias,
                                                 const float* __restrict__ resid,
                                                 u16* __restrict__ outB,
                                                 float* __restrict__ outF, int ldc) {
  __shared__ u16 As[BM * LDT];
  __shared__ u16 Bs[BN * LDT];
  int t = threadIdx.x;
  int m0 = blockIdx.y * BM, n0 = blockIdx.x * BN;
  int lane = t & 63, wid = t >> 6;
  int wm = (wid >> 1) * 64, wn = (wid & 1) * 64;
  int m16 = lane & 15, quad = lane >> 4;

  f32x4 acc[4][4] = {};

  for (int k0 = 0; k0 < K; k0 += BKG) {
    __syncthreads();
#pragma unroll
    for (int i = 0; i < 2; ++i) {
      int fi = t + i * 256;
      int row = fi >> 2, cg = (fi & 3) * 8;
      *(uint4*)&As[row * LDT + cg] = *(const uint4*)&A[(size_t)(m0 + row) * K + k0 + cg];
      *(uint4*)&Bs[row * LDT + cg] = *(const uint4*)&Bt[(size_t)(n0 + row) * K + k0 + cg];
    }
    __syncthreads();
    bf16x8 af[4], bfr[4];
#pragma unroll
    for (int i = 0; i < 4; ++i)
      af[i] = *(const bf16x8*)&As[(wm + i * 16 + m16) * LDT + quad * 8];
#pragma unroll
    for (int j = 0; j < 4; ++j)
      bfr[j] = *(const bf16x8*)&Bs[(wn + j * 16 + m16) * LDT + quad * 8];
#pragma unroll
    for (int i = 0; i < 4; ++i)
#pragma unroll
      for (int j = 0; j < 4; ++j) acc[i][j] = MFMA16(af[i], bfr[j], acc[i][j]);
  }

#pragma unroll
  for (int i = 0; i < 4; ++i)
#pragma unroll
    for (int j = 0; j < 4; ++j) {
      int col = n0 + wn + j * 16 + m16;
      float bv = (MODE == 0) ? 0.0f : bias[col];
#pragma unroll
      for (int r = 0; r < 4; ++r) {
        int row = m0 + wm + i * 16 + quad * 4 + r;
        float v = acc[i][j][r];
        if (MODE != 0) v += bv;
        if (MODE == 1) v = v > 0.0f ? v : 0.0f;
        if (MODE == 2) {
          v += resid[(size_t)row * ldc + col];
          outF[(size_t)row * ldc + col] = v;
        } else {
          outB[(size_t)row * ldc + col] = f2b(v);
        }
      }
    }
}

// ---------------------------------------------------------------- attention

// Flash attention, causal. Grid (32 qblocks reversed, 16 heads, 2 batch), 256 thr.
// Wave w: 16 q-rows (qb0 + w*16 ..). Key blocks of 32, K/V staged in LDS.
__global__ __launch_bounds__(256) void attn_kernel(const u16* __restrict__ qkv,
                                                   u16* __restrict__ attn_out) {
  int qblock = 31 - blockIdx.x;  // big blocks dispatch first
  int h = blockIdx.y, b = blockIdx.z;
  int t = threadIdx.x, lane = t & 63, w = t >> 6;
  int m16 = lane & 15, quad = lane >> 4;
  const int ldq = 3072;
  int qb0 = qblock * 64;

  // Q fragments (A-operand), scale already folded into wq pack
  int q_row = qb0 + w * 16 + m16;
  const u16* qptr = qkv + (size_t)(b * 2048 + q_row) * ldq + h * 64;
  bf16x8 qa0 = *(const bf16x8*)&qptr[quad * 8];
  bf16x8 qa1 = *(const bf16x8*)&qptr[32 + quad * 8];

  __shared__ u16 Kbuf[32 * 72];    // [key][d], pad 8
  __shared__ u16 Vt[64 * 40];      // [d][key], pad 8
  __shared__ u16 Pbuf[4][16 * 32]; // per-wave [q][key]

  f32x4 oacc[4] = {};
  float mrun[4], lrun[4];
#pragma unroll
  for (int r = 0; r < 4; ++r) {
    mrun[r] = -1e30f;
    lrun[r] = 0.0f;
  }

  int numKB = qblock * 2 + 2;
  int srow = t >> 3, scg = (t & 7) * 8;

  for (int kb0 = 0; kb0 < numKB; ++kb0) {
    int t0 = kb0 * 32;
    __syncthreads();
    {
      const u16* kg = qkv + (size_t)(b * 2048 + t0 + srow) * ldq + 1024 + h * 64 + scg;
      *(uint4*)&Kbuf[srow * 72 + scg] = *(const uint4*)kg;
      const u16* vgp = qkv + (size_t)(b * 2048 + t0 + srow) * ldq + 2048 + h * 64 + scg;
      uint4 vv = *(const uint4*)vgp;
      Vt[(scg + 0) * 40 + srow] = (u16)(vv.x & 0xffff);
      Vt[(scg + 1) * 40 + srow] = (u16)(vv.x >> 16);
      Vt[(scg + 2) * 40 + srow] = (u16)(vv.y & 0xffff);
      Vt[(scg + 3) * 40 + srow] = (u16)(vv.y >> 16);
      Vt[(scg + 4) * 40 + srow] = (u16)(vv.z & 0xffff);
      Vt[(scg + 5) * 40 + srow] = (u16)(vv.z >> 16);
      Vt[(scg + 6) * 40 + srow] = (u16)(vv.w & 0xffff);
      Vt[(scg + 7) * 40 + srow] = (u16)(vv.w >> 16);
    }
    __syncthreads();

    // S = Q K^T for 2x 16-key tiles
    f32x4 s[2];
#pragma unroll
    for (int kb = 0; kb < 2; ++kb) {
      bf16x8 bk0 = *(const bf16x8*)&Kbuf[(kb * 16 + m16) * 72 + quad * 8];
      bf16x8 bk1 = *(const bf16x8*)&Kbuf[(kb * 16 + m16) * 72 + 32 + quad * 8];
      f32x4 sa = {};
      sa = MFMA16(qa0, bk0, sa);
      sa = MFMA16(qa1, bk1, sa);
      s[kb] = sa;
    }

    // causal mask + online softmax (rows live in (quad, r), 16 key-lanes each)
#pragma unroll
    for (int r = 0; r < 4; ++r) {
      int qr = qb0 + w * 16 + quad * 4 + r;
      float s0 = s[0][r];
      if (t0 + m16 > qr) s0 = -1e30f;
      float s1 = s[1][r];
      if (t0 + 16 + m16 > qr) s1 = -1e30f;
      float mx = fmaxf(s0, s1);
#pragma unroll
      for (int d = 1; d < 16; d <<= 1) mx = fmaxf(mx, __shfl_xor(mx, d));
      float mnew = fmaxf(mrun[r], mx);
      float alpha = __expf(mrun[r] - mnew);
      float p0 = __expf(s0 - mnew), p1 = __expf(s1 - mnew);
      float ps = p0 + p1;
#pragma unroll
      for (int d = 1; d < 16; d <<= 1) ps += __shfl_xor(ps, d);
      lrun[r] = lrun[r] * alpha + ps;
      mrun[r] = mnew;
#pragma unroll
      for (int j2 = 0; j2 < 4; ++j2) oacc[j2][r] *= alpha;
      Pbuf[w][(quad * 4 + r) * 32 + m16] = f2b(p0);
      Pbuf[w][(quad * 4 + r) * 32 + 16 + m16] = f2b(p1);
    }

    // O += P V
    bf16x8 pa = *(const bf16x8*)&Pbuf[w][m16 * 32 + quad * 8];
#pragma unroll
    for (int j2 = 0; j2 < 4; ++j2) {
      bf16x8 bv = *(const bf16x8*)&Vt[(j2 * 16 + m16) * 40 + quad * 8];
      oacc[j2] = MFMA16(pa, bv, oacc[j2]);
    }
  }

#pragma unroll
  for (int j2 = 0; j2 < 4; ++j2)
#pragma unroll
    for (int r = 0; r < 4; ++r) {
      int qr = qb0 + w * 16 + quad * 4 + r;
      float v = oacc[j2][r] / lrun[r];
      attn_out[(size_t)(b * 2048 + qr) * 1024 + h * 64 + j2 * 16 + m16] = f2b(v);
    }
}

// ---------------------------------------------------------------- layernorm

__global__ __launch_bounds__(256) void ln_kernel(const float* __restrict__ in,
                                                 const float* __restrict__ g,
                                                 const float* __restrict__ be,
                                                 float* __restrict__ outF,
                                                 u16* __restrict__ outB) {
  int row = blockIdx.x;
  int t = threadIdx.x;
  const float* p = in + (size_t)row * 1024 + t * 4;
  float4 v = *(const float4*)p;
  float s = v.x + v.y + v.z + v.w;
  float sq = v.x * v.x + v.y * v.y + v.z * v.z + v.w * v.w;
#pragma unroll
  for (int d = 1; d < 64; d <<= 1) {
    s += __shfl_xor(s, d);
    sq += __shfl_xor(sq, d);
  }
  __shared__ float red[8];
  int lane = t & 63, wid = t >> 6;
  if (lane == 0) {
    red[wid] = s;
    red[4 + wid] = sq;
  }
  __syncthreads();
  s = red[0] + red[1] + red[2] + red[3];
  sq = red[4] + red[5] + red[6] + red[7];
  float mu = s * (1.0f / 1024.0f);
  float var = sq * (1.0f / 1024.0f) - mu * mu;
  float rstd = rsqrtf(var + 1e-5f);
  float4 gv = *(const float4*)(g + t * 4);
  float4 bv = *(const float4*)(be + t * 4);
  float o0 = (v.x - mu) * rstd * gv.x + bv.x;
  float o1 = (v.y - mu) * rstd * gv.y + bv.y;
  float o2 = (v.z - mu) * rstd * gv.z + bv.z;
  float o3 = (v.w - mu) * rstd * gv.w + bv.w;
  size_t o = (size_t)row * 1024 + t * 4;
  if (outF) {
    float4 ov = {o0, o1, o2, o3};
    *(float4*)(outF + o) = ov;
  }
  if (outB) {
    outB[o + 0] = f2b(o0);
    outB[o + 1] = f2b(o1);
    outB[o + 2] = f2b(o2);
    outB[o + 3] = f2b(o3);
  }
}

// ---------------------------------------------------------------- launch

extern "C" void kernel_launch(void* const* d_in, const int* in_sizes, int n_in,
                              void* d_out, int out_size, void* d_ws, size_t ws_size,
                              hipStream_t stream) {
  const float* x = (const float*)d_in[0];
  const float* wq = (const float*)d_in[1];
  const float* wk = (const float*)d_in[2];
  const float* wv = (const float*)d_in[3];
  const float* w_proj = (const float*)d_in[4];
  const float* b_proj = (const float*)d_in[5];
  const float* w1 = (const float*)d_in[6];
  const float* b1 = (const float*)d_in[7];
  const float* w2 = (const float*)d_in[8];
  const float* b2 = (const float*)d_in[9];
  const float* g1 = (const float*)d_in[10];
  const float* be1 = (const float*)d_in[11];
  const float* g2 = (const float*)d_in[12];
  const float* be2 = (const float*)d_in[13];
  float* out = (float*)d_out;

  const int M = 4096;  // B*S
  char* w = (char*)d_ws;
  u16* Xbf = (u16*)w;        w += (size_t)M * 1024 * 2;      // 8 MB
  u16* WqkvT = (u16*)w;      w += (size_t)3072 * 1024 * 2;   // 6 MB
  u16* WprojT = (u16*)w;     w += (size_t)1024 * 1024 * 2;   // 2 MB
  u16* W1T = (u16*)w;        w += (size_t)4096 * 1024 * 2;   // 8 MB
  u16* W2T = (u16*)w;        w += (size_t)1024 * 4096 * 2;   // 8 MB
  u16* QKV = (u16*)w;        w += (size_t)M * 3072 * 2;      // 24 MB
  u16* Attn = (u16*)w;       w += (size_t)M * 1024 * 2;      // 8 MB
  float* X1f = (float*)w;    w += (size_t)M * 1024 * 4;      // 16 MB
  u16* X1b = (u16*)w;        w += (size_t)M * 1024 * 2;      // 8 MB
  u16* Hbuf = QKV;  // aliases dead QKV+Attn region (32 MB), safe: sequential stream

  // 1. pack
  castx_kernel<<<M * 1024 / 1024, 256, 0, stream>>>(x, Xbf);
  tcast_qkv_kernel<<<dim3(2, 32, 48), dim3(32, 8), 0, stream>>>(wq, wk, wv, WqkvT);
  tcast_kernel<<<dim3(32, 32), dim3(32, 8), 0, stream>>>(w_proj, WprojT, 1024, 1024);
  tcast_kernel<<<dim3(128, 32), dim3(32, 8), 0, stream>>>(w1, W1T, 1024, 4096);
  tcast_kernel<<<dim3(32, 128), dim3(32, 8), 0, stream>>>(w2, W2T, 4096, 1024);

  // 2. QKV projection: [4096,1024] x [1024,3072] -> bf16
  gemm_bf16<0><<<dim3(3072 / BN, M / BM), 256, 0, stream>>>(
      Xbf, WqkvT, M, 3072, 1024, nullptr, nullptr, QKV, nullptr, 3072);

  // 3. causal flash attention -> Attn bf16 [4096,1024] head-concat
  attn_kernel<<<dim3(32, 16, 2), 256, 0, stream>>>(QKV, Attn);

  // 4. proj + bias + residual(x) -> d_out fp32
  gemm_bf16<2><<<dim3(1024 / BN, M / BM), 256, 0, stream>>>(
      Attn, WprojT, M, 1024, 1024, b_proj, x, nullptr, out, 1024);

  // 5. LN1: d_out -> X1f (fp32) + X1b (bf16)
  ln_kernel<<<M, 256, 0, stream>>>(out, g1, be1, X1f, X1b);

  // 6. MLP up: relu(X1b @ W1 + b1) -> Hbuf bf16 [4096,4096]
  gemm_bf16<1><<<dim3(4096 / BN, M / BM), 256, 0, stream>>>(
      X1b, W1T, M, 4096, 1024, b1, nullptr, Hbuf, nullptr, 4096);

  // 7. MLP down + bias + residual(X1f) -> d_out fp32
  gemm_bf16<2><<<dim3(1024 / BN, M / BM), 256, 0, stream>>>(
      Hbuf, W2T, M, 1024, 4096, b2, X1f, nullptr, out, 1024);

  // 8. LN2 in-place on d_out
  ln_kernel<<<M, 256, 0, stream>>>(out, g2, be2, out, nullptr);
}

// Round 2
// 455.223 us; speedup vs baseline: 1.2704x; 1.2704x over previous
//
#include <hip/hip_runtime.h>

// Transformer block on MI355X. bf16 MFMA for all GEMM-shaped work, fp32 stats.
// GEMM: C[M,N] = A[M,K] (row-major bf16) x Bt[N,K] (row-major bf16 = B^T).
// MFMA 16x16x32 bf16 fragments (learn_hip verified):
//   A/B frag: [m|n = lane&15][k = (lane>>4)*8 + j], 8 contiguous bf16 per lane.
//   C/D frag: col = lane&15, row = (lane>>4)*4 + reg.

typedef unsigned short u16;
typedef unsigned int u32;
typedef __attribute__((ext_vector_type(8))) short bf16x8;
typedef __attribute__((ext_vector_type(4))) float f32x4;

#define MFMA16(a, b, c) __builtin_amdgcn_mfma_f32_16x16x32_bf16(a, b, c, 0, 0, 0)

__device__ __forceinline__ u16 f2b(float f) {
  unsigned int u = __builtin_bit_cast(unsigned int, f);
  u = (u + 0x7fffu + ((u >> 16) & 1u)) >> 16;
  return (u16)u;
}

// ---------------------------------------------------------------- pack kernels

__global__ __launch_bounds__(256) void castx_kernel(const float* __restrict__ src,
                                                    u16* __restrict__ dst) {
  int i = (blockIdx.x * 256 + threadIdx.x) * 4;
  float4 v = *(const float4*)(src + i);
  dst[i + 0] = f2b(v.x);
  dst[i + 1] = f2b(v.y);
  dst[i + 2] = f2b(v.z);
  dst[i + 3] = f2b(v.w);
}

// tiled transpose+cast: dst[c*R + r] = bf16(src[r*C + c])
__global__ __launch_bounds__(256) void tcast_kernel(const float* __restrict__ src,
                                                    u16* __restrict__ dst, int R, int C) {
  __shared__ float tile[32][33];
  int tx = threadIdx.x, ty = threadIdx.y;
  int r0 = blockIdx.y * 32, c0 = blockIdx.x * 32;
#pragma unroll
  for (int i = 0; i < 4; ++i)
    tile[ty + i * 8][tx] = src[(size_t)(r0 + ty + i * 8) * C + c0 + tx];
  __syncthreads();
#pragma unroll
  for (int i = 0; i < 4; ++i)
    dst[(size_t)(c0 + ty + i * 8) * R + r0 + tx] = f2b(tile[tx][ty + i * 8]);
}

// per-(proj,head) transpose of [1024 d][64 k] into WqkvT[n=p*1024+h*64+k][d].
// q gets (1/sqrt(64))*log2(e) folded in (attn uses exp2).
__global__ __launch_bounds__(256) void tcast_qkv_kernel(const float* __restrict__ wq,
                                                        const float* __restrict__ wk,
                                                        const float* __restrict__ wv,
                                                        u16* __restrict__ dst) {
  __shared__ float tile[32][33];
  int tx = threadIdx.x, ty = threadIdx.y;
  int z = blockIdx.z;
  int p = z >> 4, h = z & 15;
  const float* src = (p == 0 ? wq : (p == 1 ? wk : wv)) + (size_t)h * 1024 * 64;
  float scale = (p == 0) ? 0.1803368801f : 1.0f;  // 0.125 * log2(e)
  u16* dbase = dst + (size_t)(p * 1024 + h * 64) * 1024;
  int r0 = blockIdx.y * 32, c0 = blockIdx.x * 32;
#pragma unroll
  for (int i = 0; i < 4; ++i)
    tile[ty + i * 8][tx] = src[(size_t)(r0 + ty + i * 8) * 64 + c0 + tx];
  __syncthreads();
#pragma unroll
  for (int i = 0; i < 4; ++i)
    dbase[(size_t)(c0 + ty + i * 8) * 1024 + r0 + tx] = f2b(tile[tx][ty + i * 8] * scale);
}

// ---------------------------------------------------------------- GEMM

// MODE 0: C bf16 (no bias) -> outB | 1: relu(C+bias) bf16 | 2: C+bias+resid fp32
#define BM 128
#define BN 128
#define BKG 32
#define LDT 40

template <int MODE>
__global__ __launch_bounds__(256) void gemm_bf16(const u16* __restrict__ A,
                                                 const u16* __restrict__ Bt, int M, int N,
                                                 int K, const float* __restrict__ bias,
                                                 const float* __restrict__ resid,
                                                 u16* __restrict__ outB,
                                                 float* __restrict__ outF, int ldc) {
  __shared__ u16 As[BM * LDT];
  __shared__ u16 Bs[BN * LDT];
  int t = threadIdx.x;
  int m0 = blockIdx.y * BM, n0 = blockIdx.x * BN;
  int lane = t & 63, wid = t >> 6;
  int wm = (wid >> 1) * 64, wn = (wid & 1) * 64;
  int m16 = lane & 15, quad = lane >> 4;

  f32x4 acc[4][4] = {};

  for (int k0 = 0; k0 < K; k0 += BKG) {
    __syncthreads();
#pragma unroll
    for (int i = 0; i < 2; ++i) {
      int fi = t + i * 256;
      int row = fi >> 2, cg = (fi & 3) * 8;
      *(uint4*)&As[row * LDT + cg] = *(const uint4*)&A[(size_t)(m0 + row) * K + k0 + cg];
      *(uint4*)&Bs[row * LDT + cg] = *(const uint4*)&Bt[(size_t)(n0 + row) * K + k0 + cg];
    }
    __syncthreads();
    bf16x8 af[4], bfr[4];
#pragma unroll
    for (int i = 0; i < 4; ++i)
      af[i] = *(const bf16x8*)&As[(wm + i * 16 + m16) * LDT + quad * 8];
#pragma unroll
    for (int j = 0; j < 4; ++j)
      bfr[j] = *(const bf16x8*)&Bs[(wn + j * 16 + m16) * LDT + quad * 8];
#pragma unroll
    for (int i = 0; i < 4; ++i)
#pragma unroll
      for (int j = 0; j < 4; ++j) acc[i][j] = MFMA16(af[i], bfr[j], acc[i][j]);
  }

#pragma unroll
  for (int i = 0; i < 4; ++i)
#pragma unroll
    for (int j = 0; j < 4; ++j) {
      int col = n0 + wn + j * 16 + m16;
      float bv = (MODE == 0) ? 0.0f : bias[col];
#pragma unroll
      for (int r = 0; r < 4; ++r) {
        int row = m0 + wm + i * 16 + quad * 4 + r;
        float v = acc[i][j][r];
        if (MODE != 0) v += bv;
        if (MODE == 1) v = v > 0.0f ? v : 0.0f;
        if (MODE == 2) {
          v += resid[(size_t)row * ldc + col];
          outF[(size_t)row * ldc + col] = v;
        } else {
          outB[(size_t)row * ldc + col] = f2b(v);
        }
      }
    }
}

// ---------------------------------------------------------------- attention v2

// Flash attention, causal. Grid (16 qblocks reversed, 16 heads, 2 batch), 256 thr.
// 4 waves x 32 q-rows = 128 q/block. 64-key tiles staged in LDS (K natural,
// V transposed via shfl+v_perm packing). Wave-shared softmax max; row-sums via
// MFMA against a ones B-fragment (no shuffle reduce). Scores arrive pre-scaled
// by 0.125*log2e so p = exp2(s - m).
__global__ __launch_bounds__(256) void attn_kernel(const u16* __restrict__ qkv,
                                                   u16* __restrict__ attn_out) {
  int qblock = 15 - blockIdx.x;  // big blocks dispatch first
  int h = blockIdx.y, b = blockIdx.z;
  int t = threadIdx.x, lane = t & 63, w = t >> 6;
  int m16 = lane & 15, quad = lane >> 4;
  const int ldq = 3072;
  int qb0 = qblock * 128;
  int wq0 = qb0 + w * 32;
  int wq_max = wq0 + 31;

  __shared__ u16 Ks[64 * 72];     // [key][d]
  __shared__ u16 Vt[64 * 72];     // [d][key]
  __shared__ u16 Pb[4][32 * 72];  // per-wave [q][t]

  // Q fragments (A-operand); scale+log2e folded into wq pack
  bf16x8 qa[2][2];
#pragma unroll
  for (int qs = 0; qs < 2; ++qs) {
    const u16* qp = qkv + (size_t)(b * 2048 + wq0 + qs * 16 + m16) * ldq + h * 64;
    qa[qs][0] = *(const bf16x8*)&qp[quad * 8];
    qa[qs][1] = *(const bf16x8*)&qp[32 + quad * 8];
  }

  bf16x8 ones;
#pragma unroll
  for (int i = 0; i < 8; ++i) ones[i] = (short)0x3F80;  // bf16 1.0

  f32x4 oacc[2][4] = {};
  f32x4 oL[2] = {};
  float mrun = -1e30f;

  int iters = 2 * qblock + 2;
  int srow = t >> 2;          // staging row (key) 0..63
  int sc = (t & 3) * 16;      // staging d-base (16 d per thread)
  int rr = srow & 15;         // row within wave's 16-row staging chunk
  int odd = rr & 1, r2 = rr & 2;

  for (int it = 0; it < iters; ++it) {
    int t0 = it * 64;
    __syncthreads();
    // ---- stage K (natural) ----
    {
      const u16* kg = qkv + (size_t)(b * 2048 + t0 + srow) * ldq + 1024 + h * 64 + sc;
      *(uint4*)&Ks[srow * 72 + sc] = *(const uint4*)&kg[0];
      *(uint4*)&Ks[srow * 72 + sc + 8] = *(const uint4*)&kg[8];
    }
    // ---- stage V transposed: Vt[d][key] ----
    {
      const u16* vg = qkv + (size_t)(b * 2048 + t0 + srow) * ldq + 2048 + h * 64 + sc;
      uint4 va = *(const uint4*)&vg[0];  // d = sc..sc+7   (2 d per u32)
      uint4 vb = *(const uint4*)&vg[8];  // d = sc+8..sc+15
      // stage 1: pair rows (rr&~1, rr|1); even lane keeps low-8 d, odd keeps high-8
      uint4 mine = odd ? vb : va;
      uint4 sendv = odd ? va : vb;
      u32 tx = __shfl_xor(sendv.x, 4), ty = __shfl_xor(sendv.y, 4);
      u32 tz = __shfl_xor(sendv.z, 4), tw = __shfl_xor(sendv.w, 4);
      u32 ke0 = odd ? tx : mine.x, ko0 = odd ? mine.x : tx;
      u32 ke1 = odd ? ty : mine.y, ko1 = odd ? mine.y : ty;
      u32 ke2 = odd ? tz : mine.z, ko2 = odd ? mine.z : tz;
      u32 ke3 = odd ? tw : mine.w, ko3 = odd ? mine.w : tw;
      u32 p[8];
      p[0] = __builtin_amdgcn_perm(ko0, ke0, 0x05040100u);
      p[1] = __builtin_amdgcn_perm(ko0, ke0, 0x07060302u);
      p[2] = __builtin_amdgcn_perm(ko1, ke1, 0x05040100u);
      p[3] = __builtin_amdgcn_perm(ko1, ke1, 0x07060302u);
      p[4] = __builtin_amdgcn_perm(ko2, ke2, 0x05040100u);
      p[5] = __builtin_amdgcn_perm(ko2, ke2, 0x07060302u);
      p[6] = __builtin_amdgcn_perm(ko3, ke3, 0x05040100u);
      p[7] = __builtin_amdgcn_perm(ko3, ke3, 0x07060302u);
      // stage 2: combine key-pairs across rows +-2; keep 4 d per lane
      u32 q0 = __shfl_xor(r2 ? p[0] : p[4], 8);
      u32 q1 = __shfl_xor(r2 ? p[1] : p[5], 8);
      u32 q2 = __shfl_xor(r2 ? p[2] : p[6], 8);
      u32 q3 = __shfl_xor(r2 ? p[3] : p[7], 8);
      int Df = sc + odd * 8 + (r2 ? 4 : 0);
      int key0 = srow & ~3;
      uint2 w0 = {r2 ? q0 : p[0], r2 ? p[4] : q0};
      uint2 w1 = {r2 ? q1 : p[1], r2 ? p[5] : q1};
      uint2 w2 = {r2 ? q2 : p[2], r2 ? p[6] : q2};
      uint2 w3 = {r2 ? q3 : p[3], r2 ? p[7] : q3};
      *(uint2*)&Vt[(Df + 0) * 72 + key0] = w0;
      *(uint2*)&Vt[(Df + 1) * 72 + key0] = w1;
      *(uint2*)&Vt[(Df + 2) * 72 + key0] = w2;
      *(uint2*)&Vt[(Df + 3) * 72 + key0] = w3;
    }
    __syncthreads();

    if (t0 > wq_max) continue;  // causal: nothing for this wave (barriers done)

    // ---- S = Q K^T : 32q x 64t ----
    f32x4 sv[2][4];
#pragma unroll
    for (int ts = 0; ts < 4; ++ts) {
      bf16x8 bk0 = *(const bf16x8*)&Ks[(ts * 16 + m16) * 72 + quad * 8];
      bf16x8 bk1 = *(const bf16x8*)&Ks[(ts * 16 + m16) * 72 + 32 + quad * 8];
#pragma unroll
      for (int qs = 0; qs < 2; ++qs) {
        f32x4 a = {};
        a = MFMA16(qa[qs][0], bk0, a);
        a = MFMA16(qa[qs][1], bk1, a);
        sv[qs][ts] = a;
      }
    }

    // ---- causal mask (only the wave's final tile straddles the diagonal) ----
    if (t0 + 63 > wq0) {
#pragma unroll
      for (int qs = 0; qs < 2; ++qs)
#pragma unroll
        for (int ts = 0; ts < 4; ++ts)
#pragma unroll
          for (int r = 0; r < 4; ++r) {
            int key = t0 + ts * 16 + m16;
            int qr = wq0 + qs * 16 + quad * 4 + r;
            if (key > qr) sv[qs][ts][r] = -3e38f;
          }
    }

    // ---- wave-shared max ----
    f32x4 m4 = sv[0][0];
#pragma unroll
    for (int qs = 0; qs < 2; ++qs)
#pragma unroll
      for (int ts = 0; ts < 4; ++ts) {
        if (qs == 0 && ts == 0) continue;
#pragma unroll
        for (int r = 0; r < 4; ++r) m4[r] = fmaxf(m4[r], sv[qs][ts][r]);
      }
    float mx = fmaxf(fmaxf(m4[0], m4[1]), fmaxf(m4[2], m4[3]));
#pragma unroll
    for (int d = 1; d < 64; d <<= 1) mx = fmaxf(mx, __shfl_xor(mx, d));

    if (mx > mrun) {  // wave-uniform rescale (rare after warm-up)
      float alpha = exp2f(mrun - mx);
#pragma unroll
      for (int qs = 0; qs < 2; ++qs) {
        oL[qs] *= alpha;
#pragma unroll
        for (int ds = 0; ds < 4; ++ds) oacc[qs][ds] *= alpha;
      }
      mrun = mx;
    }

    // ---- p = exp2(s - m), pack to bf16 (trunc), store to per-wave Pb ----
#pragma unroll
    for (int qs = 0; qs < 2; ++qs)
#pragma unroll
      for (int ts = 0; ts < 4; ++ts)
#pragma unroll
        for (int r = 0; r < 4; ++r) {
          float p = exp2f(sv[qs][ts][r] - mrun);
          Pb[w][(qs * 16 + quad * 4 + r) * 72 + ts * 16 + m16] =
              (u16)(__builtin_bit_cast(unsigned int, p) >> 16);
        }

    // ---- O += P V ; l += P * ones (row-sum via MFMA) ----
#pragma unroll
    for (int th = 0; th < 2; ++th) {
      bf16x8 pa0 = *(const bf16x8*)&Pb[w][m16 * 72 + th * 32 + quad * 8];
      bf16x8 pa1 = *(const bf16x8*)&Pb[w][(16 + m16) * 72 + th * 32 + quad * 8];
      oL[0] = MFMA16(pa0, ones, oL[0]);
      oL[1] = MFMA16(pa1, ones, oL[1]);
#pragma unroll
      for (int ds = 0; ds < 4; ++ds) {
        bf16x8 bv = *(const bf16x8*)&Vt[(ds * 16 + m16) * 72 + th * 32 + quad * 8];
        oacc[0][ds] = MFMA16(pa0, bv, oacc[0][ds]);
        oacc[1][ds] = MFMA16(pa1, bv, oacc[1][ds]);
      }
    }
  }

  // ---- epilogue: normalize, store bf16 ----
#pragma unroll
  for (int qs = 0; qs < 2; ++qs) {
    f32x4 rl;
#pragma unroll
    for (int r = 0; r < 4; ++r) rl[r] = 1.0f / oL[qs][r];
#pragma unroll
    for (int ds = 0; ds < 4; ++ds)
#pragma unroll
      for (int r = 0; r < 4; ++r) {
        int row = wq0 + qs * 16 + quad * 4 + r;
        attn_out[(size_t)(b * 2048 + row) * 1024 + h * 64 + ds * 16 + m16] =
            f2b(oacc[qs][ds][r] * rl[r]);
      }
  }
}

// ---------------------------------------------------------------- layernorm

__global__ __launch_bounds__(256) void ln_kernel(const float* __restrict__ in,
                                                 const float* __restrict__ g,
                                                 const float* __restrict__ be,
                                                 float* __restrict__ outF,
                                                 u16* __restrict__ outB) {
  int row = blockIdx.x;
  int t = threadIdx.x;
  const float* p = in + (size_t)row * 1024 + t * 4;
  float4 v = *(const float4*)p;
  float s = v.x + v.y + v.z + v.w;
  float sq = v.x * v.x + v.y * v.y + v.z * v.z + v.w * v.w;
#pragma unroll
  for (int d = 1; d < 64; d <<= 1) {
    s += __shfl_xor(s, d);
    sq += __shfl_xor(sq, d);
  }
  __shared__ float red[8];
  int lane = t & 63, wid = t >> 6;
  if (lane == 0) {
    red[wid] = s;
    red[4 + wid] = sq;
  }
  __syncthreads();
  s = red[0] + red[1] + red[2] + red[3];
  sq = red[4] + red[5] + red[6] + red[7];
  float mu = s * (1.0f / 1024.0f);
  float var = sq * (1.0f / 1024.0f) - mu * mu;
  float rstd = rsqrtf(var + 1e-5f);
  float4 gv = *(const float4*)(g + t * 4);
  float4 bv = *(const float4*)(be + t * 4);
  float o0 = (v.x - mu) * rstd * gv.x + bv.x;
  float o1 = (v.y - mu) * rstd * gv.y + bv.y;
  float o2 = (v.z - mu) * rstd * gv.z + bv.z;
  float o3 = (v.w - mu) * rstd * gv.w + bv.w;
  size_t o = (size_t)row * 1024 + t * 4;
  if (outF) {
    float4 ov = {o0, o1, o2, o3};
    *(float4*)(outF + o) = ov;
  }
  if (outB) {
    outB[o + 0] = f2b(o0);
    outB[o + 1] = f2b(o1);
    outB[o + 2] = f2b(o2);
    outB[o + 3] = f2b(o3);
  }
}

// ---------------------------------------------------------------- launch

extern "C" void kernel_launch(void* const* d_in, const int* in_sizes, int n_in,
                              void* d_out, int out_size, void* d_ws, size_t ws_size,
                              hipStream_t stream) {
  const float* x = (const float*)d_in[0];
  const float* wq = (const float*)d_in[1];
  const float* wk = (const float*)d_in[2];
  const float* wv = (const float*)d_in[3];
  const float* w_proj = (const float*)d_in[4];
  const float* b_proj = (const float*)d_in[5];
  const float* w1 = (const float*)d_in[6];
  const float* b1 = (const float*)d_in[7];
  const float* w2 = (const float*)d_in[8];
  const float* b2 = (const float*)d_in[9];
  const float* g1 = (const float*)d_in[10];
  const float* be1 = (const float*)d_in[11];
  const float* g2 = (const float*)d_in[12];
  const float* be2 = (const float*)d_in[13];
  float* out = (float*)d_out;

  const int M = 4096;  // B*S
  char* w = (char*)d_ws;
  u16* Xbf = (u16*)w;        w += (size_t)M * 1024 * 2;
  u16* WqkvT = (u16*)w;      w += (size_t)3072 * 1024 * 2;
  u16* WprojT = (u16*)w;     w += (size_t)1024 * 1024 * 2;
  u16* W1T = (u16*)w;        w += (size_t)4096 * 1024 * 2;
  u16* W2T = (u16*)w;        w += (size_t)1024 * 4096 * 2;
  u16* QKV = (u16*)w;        w += (size_t)M * 3072 * 2;
  u16* Attn = (u16*)w;       w += (size_t)M * 1024 * 2;
  float* X1f = (float*)w;    w += (size_t)M * 1024 * 4;
  u16* X1b = (u16*)w;        w += (size_t)M * 1024 * 2;
  u16* Hbuf = QKV;  // aliases dead QKV+Attn region after proj GEMM

  // 1. pack
  castx_kernel<<<M * 1024 / 1024, 256, 0, stream>>>(x, Xbf);
  tcast_qkv_kernel<<<dim3(2, 32, 48), dim3(32, 8), 0, stream>>>(wq, wk, wv, WqkvT);
  tcast_kernel<<<dim3(32, 32), dim3(32, 8), 0, stream>>>(w_proj, WprojT, 1024, 1024);
  tcast_kernel<<<dim3(128, 32), dim3(32, 8), 0, stream>>>(w1, W1T, 1024, 4096);
  tcast_kernel<<<dim3(32, 128), dim3(32, 8), 0, stream>>>(w2, W2T, 4096, 1024);

  // 2. QKV projection
  gemm_bf16<0><<<dim3(3072 / BN, M / BM), 256, 0, stream>>>(
      Xbf, WqkvT, M, 3072, 1024, nullptr, nullptr, QKV, nullptr, 3072);

  // 3. causal flash attention
  attn_kernel<<<dim3(16, 16, 2), 256, 0, stream>>>(QKV, Attn);

  // 4. proj + bias + residual(x) -> d_out fp32
  gemm_bf16<2><<<dim3(1024 / BN, M / BM), 256, 0, stream>>>(
      Attn, WprojT, M, 1024, 1024, b_proj, x, nullptr, out, 1024);

  // 5. LN1
  ln_kernel<<<M, 256, 0, stream>>>(out, g1, be1, X1f, X1b);

  // 6. MLP up
  gemm_bf16<1><<<dim3(4096 / BN, M / BM), 256, 0, stream>>>(
      X1b, W1T, M, 4096, 1024, b1, nullptr, Hbuf, nullptr, 4096);

  // 7. MLP down + residual
  gemm_bf16<2><<<dim3(1024 / BN, M / BM), 256, 0, stream>>>(
      Hbuf, W2T, M, 1024, 4096, b2, X1f, nullptr, out, 1024);

  // 8. LN2 in-place
  ln_kernel<<<M, 256, 0, stream>>>(out, g2, be2, out, nullptr);
}

// Round 4
// 452.537 us; speedup vs baseline: 1.2780x; 1.0059x over previous
//
#include <hip/hip_runtime.h>

// Transformer block on MI355X. bf16 MFMA for GEMMs/QK^T, fp16 MFMA for PV, fp32 stats.
// GEMM: C[M,N] = A[M,K] (row-major bf16) x Bt[N,K] (row-major bf16 = B^T).
// MFMA 16x16x32 bf16 frags: A/B [idx=lane&15][k=quad*8+j]; C/D col=lane&15, row=quad*4+reg.
// MFMA 16x16x16 f16 frags:  A/B [idx=lane&15][k=quad*4+j]; C/D same 16x16 layout.
// Key identity used in attention: S^T C-layout == 16x16x16 B-operand layout, so
// P^T goes from QK^T MFMA output straight into the PV MFMA with no LDS round-trip.

typedef unsigned short u16;
typedef unsigned int u32;
typedef __attribute__((ext_vector_type(8))) short bf16x8;
typedef __attribute__((ext_vector_type(4))) float f32x4;
typedef __attribute__((ext_vector_type(2))) u32 u32x2;
typedef __attribute__((ext_vector_type(4))) _Float16 f16x4;

#define MFMA16(a, b, c) __builtin_amdgcn_mfma_f32_16x16x32_bf16(a, b, c, 0, 0, 0)
#define MFMAH(a, b, c) __builtin_amdgcn_mfma_f32_16x16x16f16(a, b, c, 0, 0, 0)

__device__ __forceinline__ u16 f2b(float f) {
  unsigned int u = __builtin_bit_cast(unsigned int, f);
  u = (u + 0x7fffu + ((u >> 16) & 1u)) >> 16;
  return (u16)u;
}

// async 16B/lane global->LDS. lds base must be wave-uniform; lane i lands at
// base + i*16B (m97 pattern, 874 TF).
__device__ __forceinline__ void gload_lds16(const u16* g, u16* l) {
  __builtin_amdgcn_global_load_lds((const __attribute__((address_space(1))) void*)g,
                                   (__attribute__((address_space(3))) void*)l, 16, 0, 0);
}

// two f32 -> packed two f16 in a u32 (v_cvt_pkrtz_f16_f32)
__device__ __forceinline__ u32 pkrtz(float lo, float hi) {
  return __builtin_bit_cast(u32, __builtin_amdgcn_cvt_pkrtz(lo, hi));
}

// u32 holding two bf16 -> two f16 (positions preserved)
__device__ __forceinline__ u32 bf2h2(u32 u) {
  float lo = __builtin_bit_cast(float, u << 16);
  float hi = __builtin_bit_cast(float, u & 0xFFFF0000u);
  return pkrtz(lo, hi);
}

__device__ __forceinline__ f16x4 pack4h(float a, float b, float c, float d) {
  u32x2 r = {pkrtz(a, b), pkrtz(c, d)};
  return __builtin_bit_cast(f16x4, r);
}

// ---------------------------------------------------------------- pack kernels

__global__ __launch_bounds__(256) void castx_kernel(const float* __restrict__ src,
                                                    u16* __restrict__ dst) {
  int i = (blockIdx.x * 256 + threadIdx.x) * 4;
  float4 v = *(const float4*)(src + i);
  dst[i + 0] = f2b(v.x);
  dst[i + 1] = f2b(v.y);
  dst[i + 2] = f2b(v.z);
  dst[i + 3] = f2b(v.w);
}

// tiled transpose+cast: dst[c*R + r] = bf16(src[r*C + c])
__global__ __launch_bounds__(256) void tcast_kernel(const float* __restrict__ src,
                                                    u16* __restrict__ dst, int R, int C) {
  __shared__ float tile[32][33];
  int tx = threadIdx.x, ty = threadIdx.y;
  int r0 = blockIdx.y * 32, c0 = blockIdx.x * 32;
#pragma unroll
  for (int i = 0; i < 4; ++i)
    tile[ty + i * 8][tx] = src[(size_t)(r0 + ty + i * 8) * C + c0 + tx];
  __syncthreads();
#pragma unroll
  for (int i = 0; i < 4; ++i)
    dst[(size_t)(c0 + ty + i * 8) * R + r0 + tx] = f2b(tile[tx][ty + i * 8]);
}

// per-(proj,head) transpose of [1024 d][64 k] into WqkvT[n=p*1024+h*64+k][d].
// q gets (1/sqrt(64))*log2(e) folded in (attn uses exp2).
__global__ __launch_bounds__(256) void tcast_qkv_kernel(const float* __restrict__ wq,
                                                        const float* __restrict__ wk,
                                                        const float* __restrict__ wv,
                                                        u16* __restrict__ dst) {
  __shared__ float tile[32][33];
  int tx = threadIdx.x, ty = threadIdx.y;
  int z = blockIdx.z;
  int p = z >> 4, h = z & 15;
  const float* src = (p == 0 ? wq : (p == 1 ? wk : wv)) + (size_t)h * 1024 * 64;
  float scale = (p == 0) ? 0.1803368801f : 1.0f;  // 0.125 * log2(e)
  u16* dbase = dst + (size_t)(p * 1024 + h * 64) * 1024;
  int r0 = blockIdx.y * 32, c0 = blockIdx.x * 32;
#pragma unroll
  for (int i = 0; i < 4; ++i)
    tile[ty + i * 8][tx] = src[(size_t)(r0 + ty + i * 8) * 64 + c0 + tx];
  __syncthreads();
#pragma unroll
  for (int i = 0; i < 4; ++i)
    dbase[(size_t)(c0 + ty + i * 8) * 1024 + r0 + tx] = f2b(tile[tx][ty + i * 8] * scale);
}

// ---------------------------------------------------------------- GEMM (m97 structure)

// MODE 0: C bf16 (no bias) -> outB | 1: relu(C+bias) bf16 | 2: C+bias+resid fp32
#define BM 128
#define BN 128
#define BKG 32

template <int MODE>
__global__ __launch_bounds__(256) void gemm_bf16(const u16* __restrict__ A,
                                                 const u16* __restrict__ Bt, int M, int N,
                                                 int K, const float* __restrict__ bias,
                                                 const float* __restrict__ resid,
                                                 u16* __restrict__ outB,
                                                 float* __restrict__ outF, int ldc) {
  __shared__ u16 As[BM * BKG];  // unpadded row-major [128][32] (global_load_lds layout)
  __shared__ u16 Bs[BN * BKG];
  int t = threadIdx.x;
  int m0 = blockIdx.y * BM, n0 = blockIdx.x * BN;
  int lane = t & 63, wid = t >> 6;
  int wm = (wid >> 1) * 64, wn = (wid & 1) * 64;
  int m16 = lane & 15, quad = lane >> 4;
  int srow = wid * 32 + (lane >> 2);  // staging row (+0 / +16)
  int scol = (lane & 3) * 8;

  f32x4 acc[4][4] = {};

  for (int k0 = 0; k0 < K; k0 += BKG) {
    __syncthreads();
    gload_lds16(&A[(size_t)(m0 + srow) * K + k0 + scol], &As[(wid * 32) * BKG]);
    gload_lds16(&A[(size_t)(m0 + srow + 16) * K + k0 + scol], &As[(wid * 32 + 16) * BKG]);
    gload_lds16(&Bt[(size_t)(n0 + srow) * K + k0 + scol], &Bs[(wid * 32) * BKG]);
    gload_lds16(&Bt[(size_t)(n0 + srow + 16) * K + k0 + scol], &Bs[(wid * 32 + 16) * BKG]);
    __syncthreads();  // compiler emits vmcnt(0) drain here
    bf16x8 af[4], bfr[4];
#pragma unroll
    for (int i = 0; i < 4; ++i)
      af[i] = *(const bf16x8*)&As[(wm + i * 16 + m16) * BKG + quad * 8];
#pragma unroll
    for (int j = 0; j < 4; ++j)
      bfr[j] = *(const bf16x8*)&Bs[(wn + j * 16 + m16) * BKG + quad * 8];
#pragma unroll
    for (int i = 0; i < 4; ++i)
#pragma unroll
      for (int j = 0; j < 4; ++j) acc[i][j] = MFMA16(af[i], bfr[j], acc[i][j]);
  }

#pragma unroll
  for (int i = 0; i < 4; ++i)
#pragma unroll
    for (int j = 0; j < 4; ++j) {
      int col = n0 + wn + j * 16 + m16;
      float bv = (MODE == 0) ? 0.0f : bias[col];
#pragma unroll
      for (int r = 0; r < 4; ++r) {
        int row = m0 + wm + i * 16 + quad * 4 + r;
        float v = acc[i][j][r];
        if (MODE != 0) v += bv;
        if (MODE == 1) v = v > 0.0f ? v : 0.0f;
        if (MODE == 2) {
          v += resid[(size_t)row * ldc + col];
          outF[(size_t)row * ldc + col] = v;
        } else {
          outB[(size_t)row * ldc + col] = f2b(v);
        }
      }
    }
}

// ---------------------------------------------------------------- attention v3

// Flash attention, causal. Grid (16 qblocks reversed, 16 heads, 2 batch), 256 thr.
// 4 waves x 32 q-rows. 64-key tiles in LDS (K natural bf16, V transposed to f16).
// S^T = K*Q^T (bf16 x32 MFMA); P^T packed in-register to f16 B-frags; O^T = V^T*P^T
// (f16 x16 MFMA). No P LDS round-trip. Wave-shared max; l accumulated per-lane,
// reduced once in epilogue. Scores pre-scaled by 0.125*log2e -> p = exp2(s - m).
__global__ __launch_bounds__(256) void attn_kernel(const u16* __restrict__ qkv,
                                                   u16* __restrict__ attn_out) {
  int qblock = 15 - blockIdx.x;  // big blocks dispatch first
  int h = blockIdx.y, b = blockIdx.z;
  int t = threadIdx.x, lane = t & 63, w = t >> 6;
  int m16 = lane & 15, quad = lane >> 4;
  const int ldq = 3072;
  int qb0 = qblock * 128;
  int wq0 = qb0 + w * 32;
  int wq_max = wq0 + 31;

  __shared__ u16 Ks[64 * 72];  // [key][d] bf16
  __shared__ u16 Vt[64 * 72];  // [d][key] f16

  // Q fragments (B-operand of S^T MFMA); scale+log2e folded into wq pack
  bf16x8 qa[2][2];
#pragma unroll
  for (int qs = 0; qs < 2; ++qs) {
    const u16* qp = qkv + (size_t)(b * 2048 + wq0 + qs * 16 + m16) * ldq + h * 64;
    qa[qs][0] = *(const bf16x8*)&qp[quad * 8];
    qa[qs][1] = *(const bf16x8*)&qp[32 + quad * 8];
  }

  f32x4 oT[2][4] = {};   // O^T tiles: [qs][ds], row=d-local, col=q-local
  f32x4 lacc[2] = {};    // per-lane partial row sums (quad-partial)
  float mrun = -1e30f;

  int iters = 2 * qblock + 2;
  int srow = t >> 2;      // staging key row 0..63
  int sc = (t & 3) * 16;  // staging d-base
  int rr = srow & 15;
  int odd = rr & 1, r2 = rr & 2;

  for (int it = 0; it < iters; ++it) {
    int t0 = it * 64;
    __syncthreads();
    // ---- stage K (natural, bf16) ----
    {
      const u16* kg = qkv + (size_t)(b * 2048 + t0 + srow) * ldq + 1024 + h * 64 + sc;
      *(uint4*)&Ks[srow * 72 + sc] = *(const uint4*)&kg[0];
      *(uint4*)&Ks[srow * 72 + sc + 8] = *(const uint4*)&kg[8];
    }
    // ---- stage V transposed: Vt[d][key], converted bf16 -> f16 ----
    {
      const u16* vg = qkv + (size_t)(b * 2048 + t0 + srow) * ldq + 2048 + h * 64 + sc;
      uint4 va = *(const uint4*)&vg[0];
      uint4 vb = *(const uint4*)&vg[8];
      uint4 mine = odd ? vb : va;
      uint4 sendv = odd ? va : vb;
      u32 tx = __shfl_xor(sendv.x, 4), ty = __shfl_xor(sendv.y, 4);
      u32 tz = __shfl_xor(sendv.z, 4), tw = __shfl_xor(sendv.w, 4);
      u32 ke0 = odd ? tx : mine.x, ko0 = odd ? mine.x : tx;
      u32 ke1 = odd ? ty : mine.y, ko1 = odd ? mine.y : ty;
      u32 ke2 = odd ? tz : mine.z, ko2 = odd ? mine.z : tz;
      u32 ke3 = odd ? tw : mine.w, ko3 = odd ? mine.w : tw;
      u32 p[8];
      p[0] = __builtin_amdgcn_perm(ko0, ke0, 0x05040100u);
      p[1] = __builtin_amdgcn_perm(ko0, ke0, 0x07060302u);
      p[2] = __builtin_amdgcn_perm(ko1, ke1, 0x05040100u);
      p[3] = __builtin_amdgcn_perm(ko1, ke1, 0x07060302u);
      p[4] = __builtin_amdgcn_perm(ko2, ke2, 0x05040100u);
      p[5] = __builtin_amdgcn_perm(ko2, ke2, 0x07060302u);
      p[6] = __builtin_amdgcn_perm(ko3, ke3, 0x05040100u);
      p[7] = __builtin_amdgcn_perm(ko3, ke3, 0x07060302u);
      u32 q0 = __shfl_xor(r2 ? p[0] : p[4], 8);
      u32 q1 = __shfl_xor(r2 ? p[1] : p[5], 8);
      u32 q2 = __shfl_xor(r2 ? p[2] : p[6], 8);
      u32 q3 = __shfl_xor(r2 ? p[3] : p[7], 8);
      int Df = sc + odd * 8 + (r2 ? 4 : 0);
      int key0 = srow & ~3;
      u32x2 w0 = {bf2h2(r2 ? q0 : p[0]), bf2h2(r2 ? p[4] : q0)};
      u32x2 w1 = {bf2h2(r2 ? q1 : p[1]), bf2h2(r2 ? p[5] : q1)};
      u32x2 w2 = {bf2h2(r2 ? q2 : p[2]), bf2h2(r2 ? p[6] : q2)};
      u32x2 w3 = {bf2h2(r2 ? q3 : p[3]), bf2h2(r2 ? p[7] : q3)};
      *(u32x2*)&Vt[(Df + 0) * 72 + key0] = w0;
      *(u32x2*)&Vt[(Df + 1) * 72 + key0] = w1;
      *(u32x2*)&Vt[(Df + 2) * 72 + key0] = w2;
      *(u32x2*)&Vt[(Df + 3) * 72 + key0] = w3;
    }
    __syncthreads();

    if (t0 > wq_max) continue;  // causal: nothing for this wave (barriers done)

    // ---- S^T = K Q^T : rows t, cols q ----
    f32x4 sv[2][4];
#pragma unroll
    for (int ts = 0; ts < 4; ++ts) {
      bf16x8 ka0 = *(const bf16x8*)&Ks[(ts * 16 + m16) * 72 + quad * 8];
      bf16x8 ka1 = *(const bf16x8*)&Ks[(ts * 16 + m16) * 72 + 32 + quad * 8];
#pragma unroll
      for (int qs = 0; qs < 2; ++qs) {
        f32x4 a = {};
        a = MFMA16(ka0, qa[qs][0], a);
        a = MFMA16(ka1, qa[qs][1], a);
        sv[qs][ts] = a;
      }
    }

    // ---- causal mask (rows are keys now) ----
    if (t0 + 63 > wq0) {
#pragma unroll
      for (int qs = 0; qs < 2; ++qs)
#pragma unroll
        for (int ts = 0; ts < 4; ++ts)
#pragma unroll
          for (int r = 0; r < 4; ++r) {
            int key = t0 + ts * 16 + quad * 4 + r;
            int qr = wq0 + qs * 16 + m16;
            if (key > qr) sv[qs][ts][r] = -3e38f;
          }
    }

    // ---- wave-shared max ----
    f32x4 m4 = sv[0][0];
#pragma unroll
    for (int qs = 0; qs < 2; ++qs)
#pragma unroll
      for (int ts = 0; ts < 4; ++ts) {
        if (qs == 0 && ts == 0) continue;
#pragma unroll
        for (int r = 0; r < 4; ++r) m4[r] = fmaxf(m4[r], sv[qs][ts][r]);
      }
    float mx = fmaxf(fmaxf(m4[0], m4[1]), fmaxf(m4[2], m4[3]));
#pragma unroll
    for (int d = 1; d < 64; d <<= 1) mx = fmaxf(mx, __shfl_xor(mx, d));

    if (mx > mrun) {  // wave-uniform rescale
      float alpha = exp2f(mrun - mx);
#pragma unroll
      for (int qs = 0; qs < 2; ++qs) {
        lacc[qs] *= alpha;
#pragma unroll
        for (int ds = 0; ds < 4; ++ds) oT[qs][ds] *= alpha;
      }
      mrun = mx;
    }

    // ---- p = exp2(s - m); accumulate l; pack P^T to f16 B-frags (in-register) ----
    f16x4 pf[2][4];
#pragma unroll
    for (int qs = 0; qs < 2; ++qs)
#pragma unroll
      for (int ts = 0; ts < 4; ++ts) {
        float p0 = exp2f(sv[qs][ts][0] - mrun);
        float p1 = exp2f(sv[qs][ts][1] - mrun);
        float p2 = exp2f(sv[qs][ts][2] - mrun);
        float p3 = exp2f(sv[qs][ts][3] - mrun);
        lacc[qs][0] += p0;
        lacc[qs][1] += p1;
        lacc[qs][2] += p2;
        lacc[qs][3] += p3;
        pf[qs][ts] = pack4h(p0, p1, p2, p3);
      }

    // ---- O^T += V^T P^T  (f16 16x16x16 MFMAs) ----
#pragma unroll
    for (int ts = 0; ts < 4; ++ts)
#pragma unroll
      for (int ds = 0; ds < 4; ++ds) {
        f16x4 av = __builtin_bit_cast(
            f16x4, *(const u32x2*)&Vt[(ds * 16 + m16) * 72 + ts * 16 + quad * 4]);
        oT[0][ds] = MFMAH(av, pf[0][ts], oT[0][ds]);
        oT[1][ds] = MFMAH(av, pf[1][ts], oT[1][ds]);
      }
  }

  // ---- epilogue: reduce l across quads, normalize, store bf16 (4 d per lane) ----
#pragma unroll
  for (int qs = 0; qs < 2; ++qs) {
    float ls = lacc[qs][0] + lacc[qs][1] + lacc[qs][2] + lacc[qs][3];
    ls += __shfl_xor(ls, 16);
    ls += __shfl_xor(ls, 32);
    float rl = 1.0f / ls;
    int q = wq0 + qs * 16 + m16;
#pragma unroll
    for (int ds = 0; ds < 4; ++ds) {
      f32x4 o = oT[qs][ds];
      u32x2 ov = {(u32)f2b(o[0] * rl) | ((u32)f2b(o[1] * rl) << 16),
                  (u32)f2b(o[2] * rl) | ((u32)f2b(o[3] * rl) << 16)};
      *(u32x2*)&attn_out[(size_t)(b * 2048 + q) * 1024 + h * 64 + ds * 16 + quad * 4] = ov;
    }
  }
}

// ---------------------------------------------------------------- layernorm

__global__ __launch_bounds__(256) void ln_kernel(const float* __restrict__ in,
                                                 const float* __restrict__ g,
                                                 const float* __restrict__ be,
                                                 float* __restrict__ outF,
                                                 u16* __restrict__ outB) {
  int row = blockIdx.x;
  int t = threadIdx.x;
  const float* p = in + (size_t)row * 1024 + t * 4;
  float4 v = *(const float4*)p;
  float s = v.x + v.y + v.z + v.w;
  float sq = v.x * v.x + v.y * v.y + v.z * v.z + v.w * v.w;
#pragma unroll
  for (int d = 1; d < 64; d <<= 1) {
    s += __shfl_xor(s, d);
    sq += __shfl_xor(sq, d);
  }
  __shared__ float red[8];
  int lane = t & 63, wid = t >> 6;
  if (lane == 0) {
    red[wid] = s;
    red[4 + wid] = sq;
  }
  __syncthreads();
  s = red[0] + red[1] + red[2] + red[3];
  sq = red[4] + red[5] + red[6] + red[7];
  float mu = s * (1.0f / 1024.0f);
  float var = sq * (1.0f / 1024.0f) - mu * mu;
  float rstd = rsqrtf(var + 1e-5f);
  float4 gv = *(const float4*)(g + t * 4);
  float4 bv = *(const float4*)(be + t * 4);
  float o0 = (v.x - mu) * rstd * gv.x + bv.x;
  float o1 = (v.y - mu) * rstd * gv.y + bv.y;
  float o2 = (v.z - mu) * rstd * gv.z + bv.z;
  float o3 = (v.w - mu) * rstd * gv.w + bv.w;
  size_t o = (size_t)row * 1024 + t * 4;
  if (outF) {
    float4 ov = {o0, o1, o2, o3};
    *(float4*)(outF + o) = ov;
  }
  if (outB) {
    outB[o + 0] = f2b(o0);
    outB[o + 1] = f2b(o1);
    outB[o + 2] = f2b(o2);
    outB[o + 3] = f2b(o3);
  }
}

// ---------------------------------------------------------------- launch

extern "C" void kernel_launch(void* const* d_in, const int* in_sizes, int n_in,
                              void* d_out, int out_size, void* d_ws, size_t ws_size,
                              hipStream_t stream) {
  const float* x = (const float*)d_in[0];
  const float* wq = (const float*)d_in[1];
  const float* wk = (const float*)d_in[2];
  const float* wv = (const float*)d_in[3];
  const float* w_proj = (const float*)d_in[4];
  const float* b_proj = (const float*)d_in[5];
  const float* w1 = (const float*)d_in[6];
  const float* b1 = (const float*)d_in[7];
  const float* w2 = (const float*)d_in[8];
  const float* b2 = (const float*)d_in[9];
  const float* g1 = (const float*)d_in[10];
  const float* be1 = (const float*)d_in[11];
  const float* g2 = (const float*)d_in[12];
  const float* be2 = (const float*)d_in[13];
  float* out = (float*)d_out;

  const int M = 4096;  // B*S
  char* w = (char*)d_ws;
  u16* Xbf = (u16*)w;        w += (size_t)M * 1024 * 2;
  u16* WqkvT = (u16*)w;      w += (size_t)3072 * 1024 * 2;
  u16* WprojT = (u16*)w;     w += (size_t)1024 * 1024 * 2;
  u16* W1T = (u16*)w;        w += (size_t)4096 * 1024 * 2;
  u16* W2T = (u16*)w;        w += (size_t)1024 * 4096 * 2;
  u16* QKV = (u16*)w;        w += (size_t)M * 3072 * 2;
  u16* Attn = (u16*)w;       w += (size_t)M * 1024 * 2;
  float* X1f = (float*)w;    w += (size_t)M * 1024 * 4;
  u16* X1b = (u16*)w;        w += (size_t)M * 1024 * 2;
  u16* Hbuf = QKV;  // aliases dead QKV+Attn region after proj GEMM

  // 1. pack
  castx_kernel<<<M * 1024 / 1024, 256, 0, stream>>>(x, Xbf);
  tcast_qkv_kernel<<<dim3(2, 32, 48), dim3(32, 8), 0, stream>>>(wq, wk, wv, WqkvT);
  tcast_kernel<<<dim3(32, 32), dim3(32, 8), 0, stream>>>(w_proj, WprojT, 1024, 1024);
  tcast_kernel<<<dim3(128, 32), dim3(32, 8), 0, stream>>>(w1, W1T, 1024, 4096);
  tcast_kernel<<<dim3(32, 128), dim3(32, 8), 0, stream>>>(w2, W2T, 4096, 1024);

  // 2. QKV projection
  gemm_bf16<0><<<dim3(3072 / BN, M / BM), 256, 0, stream>>>(
      Xbf, WqkvT, M, 3072, 1024, nullptr, nullptr, QKV, nullptr, 3072);

  // 3. causal flash attention
  attn_kernel<<<dim3(16, 16, 2), 256, 0, stream>>>(QKV, Attn);

  // 4. proj + bias + residual(x) -> d_out fp32
  gemm_bf16<2><<<dim3(1024 / BN, M / BM), 256, 0, stream>>>(
      Attn, WprojT, M, 1024, 1024, b_proj, x, nullptr, out, 1024);

  // 5. LN1
  ln_kernel<<<M, 256, 0, stream>>>(out, g1, be1, X1f, X1b);

  // 6. MLP up
  gemm_bf16<1><<<dim3(4096 / BN, M / BM), 256, 0, stream>>>(
      X1b, W1T, M, 4096, 1024, b1, nullptr, Hbuf, nullptr, 4096);

  // 7. MLP down + residual
  gemm_bf16<2><<<dim3(1024 / BN, M / BM), 256, 0, stream>>>(
      Hbuf, W2T, M, 1024, 4096, b2, X1f, nullptr, out, 1024);

  // 8. LN2 in-place
  ln_kernel<<<M, 256, 0, stream>>>(out, g2, be2, out, nullptr);
}

// Round 5
// 438.709 us; speedup vs baseline: 1.3183x; 1.0315x over previous
//
#include <hip/hip_runtime.h>

// Transformer block on MI355X. bf16 MFMA for GEMMs/QK^T, fp16 MFMA for PV, fp32 stats.
// GEMM: C[M,N] = A[M,K] (row-major bf16) x Bt[N,K] (row-major bf16 = B^T).
// MFMA 16x16x32 bf16 frags: A/B [idx=lane&15][k=quad*8+j]; C/D col=lane&15, row=quad*4+reg.
// MFMA 16x16x16 f16 frags:  A/B [idx=lane&15][k=quad*4+j]; C/D same 16x16 layout.
// Attention identity: S^T C-layout == 16x16x16 B-operand layout, so P^T goes from
// the QK^T MFMA output straight into the PV MFMA with no LDS round-trip.

typedef unsigned short u16;
typedef unsigned int u32;
typedef __attribute__((ext_vector_type(8))) short bf16x8;
typedef __attribute__((ext_vector_type(4))) float f32x4;
typedef __attribute__((ext_vector_type(2))) u32 u32x2;
typedef __attribute__((ext_vector_type(4))) _Float16 f16x4;

#define MFMA16(a, b, c) __builtin_amdgcn_mfma_f32_16x16x32_bf16(a, b, c, 0, 0, 0)
#define MFMAH(a, b, c) __builtin_amdgcn_mfma_f32_16x16x16f16(a, b, c, 0, 0, 0)

__device__ __forceinline__ u16 f2b(float f) {
  unsigned int u = __builtin_bit_cast(unsigned int, f);
  u = (u + 0x7fffu + ((u >> 16) & 1u)) >> 16;
  return (u16)u;
}

// async 16B/lane global->LDS; LDS dst = wave-uniform base + lane*16.
__device__ __forceinline__ void gload_lds16(const u16* g, u16* l) {
  __builtin_amdgcn_global_load_lds((const __attribute__((address_space(1))) void*)g,
                                   (__attribute__((address_space(3))) void*)l, 16, 0, 0);
}

__device__ __forceinline__ u32 pkrtz(float lo, float hi) {
  return __builtin_bit_cast(u32, __builtin_amdgcn_cvt_pkrtz(lo, hi));
}

// u32 holding two bf16 -> two f16 (positions preserved)
__device__ __forceinline__ u32 bf2h2(u32 u) {
  float lo = __builtin_bit_cast(float, u << 16);
  float hi = __builtin_bit_cast(float, u & 0xFFFF0000u);
  return pkrtz(lo, hi);
}

__device__ __forceinline__ f16x4 pack4h(float a, float b, float c, float d) {
  u32x2 r = {pkrtz(a, b), pkrtz(c, d)};
  return __builtin_bit_cast(f16x4, r);
}

// ---------------------------------------------------------------- pack kernels

__global__ __launch_bounds__(256) void castx_kernel(const float* __restrict__ src,
                                                    u16* __restrict__ dst) {
  int i = (blockIdx.x * 256 + threadIdx.x) * 4;
  float4 v = *(const float4*)(src + i);
  dst[i + 0] = f2b(v.x);
  dst[i + 1] = f2b(v.y);
  dst[i + 2] = f2b(v.z);
  dst[i + 3] = f2b(v.w);
}

// tiled transpose+cast: dst[c*R + r] = bf16(src[r*C + c])
__global__ __launch_bounds__(256) void tcast_kernel(const float* __restrict__ src,
                                                    u16* __restrict__ dst, int R, int C) {
  __shared__ float tile[32][33];
  int tx = threadIdx.x, ty = threadIdx.y;
  int r0 = blockIdx.y * 32, c0 = blockIdx.x * 32;
#pragma unroll
  for (int i = 0; i < 4; ++i)
    tile[ty + i * 8][tx] = src[(size_t)(r0 + ty + i * 8) * C + c0 + tx];
  __syncthreads();
#pragma unroll
  for (int i = 0; i < 4; ++i)
    dst[(size_t)(c0 + ty + i * 8) * R + r0 + tx] = f2b(tile[tx][ty + i * 8]);
}

// per-(proj,head) transpose of [1024 d][64 k] into WqkvT[n=p*1024+h*64+k][d].
// q gets (1/sqrt(64))*log2(e) folded in (attn uses exp2).
__global__ __launch_bounds__(256) void tcast_qkv_kernel(const float* __restrict__ wq,
                                                        const float* __restrict__ wk,
                                                        const float* __restrict__ wv,
                                                        u16* __restrict__ dst) {
  __shared__ float tile[32][33];
  int tx = threadIdx.x, ty = threadIdx.y;
  int z = blockIdx.z;
  int p = z >> 4, h = z & 15;
  const float* src = (p == 0 ? wq : (p == 1 ? wk : wv)) + (size_t)h * 1024 * 64;
  float scale = (p == 0) ? 0.1803368801f : 1.0f;  // 0.125 * log2(e)
  u16* dbase = dst + (size_t)(p * 1024 + h * 64) * 1024;
  int r0 = blockIdx.y * 32, c0 = blockIdx.x * 32;
#pragma unroll
  for (int i = 0; i < 4; ++i)
    tile[ty + i * 8][tx] = src[(size_t)(r0 + ty + i * 8) * 64 + c0 + tx];
  __syncthreads();
#pragma unroll
  for (int i = 0; i < 4; ++i)
    dbase[(size_t)(c0 + ty + i * 8) * 1024 + r0 + tx] = f2b(tile[tx][ty + i * 8] * scale);
}

// ---------------------------------------------------------------- GEMM v2
// BK=64; LDS dense [rows][64] staged via global_load_lds with 16B-chunk XOR
// swizzle (chunk c of row r lives at slot c^(r&7)) -> b128 frag reads are
// 2-addr/bank (free). BN=128: wave grid 2x2 (64x64/wave). BN=64: 4x1 (32x64).
// MODE 0: C bf16 -> outB | 1: relu(C+bias) bf16 | 2: C+bias+resid fp32

template <int MODE, int BN>
__global__ __launch_bounds__(256) void gemm_bf16(const u16* __restrict__ A,
                                                 const u16* __restrict__ Bt, int M, int N,
                                                 int K, const float* __restrict__ bias,
                                                 const float* __restrict__ resid,
                                                 u16* __restrict__ outB,
                                                 float* __restrict__ outF, int ldc) {
  constexpr int BM = 128, BK = 64;
  constexpr int IM = (BN == 128) ? 4 : 2;  // 16-row tiles per wave
  constexpr int JN = 4;                    // 16-col tiles per wave
  __shared__ u16 As[BM * BK];
  __shared__ u16 Bs[BN * BK];
  int t = threadIdx.x;
  int m0 = blockIdx.y * BM, n0 = blockIdx.x * BN;
  int lane = t & 63, wid = t >> 6;
  int wm = (BN == 128) ? (wid >> 1) * 64 : wid * 32;
  int wn = (BN == 128) ? (wid & 1) * 64 : 0;
  int m16 = lane & 15, quad = lane >> 4;
  int sw = m16 & 7;  // read-side swizzle key (row&7 == m16&7 for 16-aligned tiles)

  f32x4 acc[IM][JN] = {};

  for (int k0 = 0; k0 < K; k0 += BK) {
    __syncthreads();
#pragma unroll
    for (int i = 0; i < 4; ++i) {  // A: 1024 slots
      int S = i * 256 + t;
      int row = S >> 3, c = S & 7;
      gload_lds16(&A[(size_t)(m0 + row) * K + k0 + (c ^ (row & 7)) * 8],
                  &As[(i * 256 + wid * 64) * 8]);
    }
#pragma unroll
    for (int i = 0; i < BN / 32; ++i) {  // B: BN*8 slots
      int S = i * 256 + t;
      int row = S >> 3, c = S & 7;
      gload_lds16(&Bt[(size_t)(n0 + row) * K + k0 + (c ^ (row & 7)) * 8],
                  &Bs[(i * 256 + wid * 64) * 8]);
    }
    __syncthreads();
#pragma unroll
    for (int kk = 0; kk < 2; ++kk) {
      bf16x8 af[IM], bfr[JN];
      int slot = (kk * 4 + quad) ^ sw;
#pragma unroll
      for (int i = 0; i < IM; ++i)
        af[i] = *(const bf16x8*)&As[(wm + i * 16 + m16) * BK + slot * 8];
#pragma unroll
      for (int j = 0; j < JN; ++j)
        bfr[j] = *(const bf16x8*)&Bs[(wn + j * 16 + m16) * BK + slot * 8];
#pragma unroll
      for (int i = 0; i < IM; ++i)
#pragma unroll
        for (int j = 0; j < JN; ++j) acc[i][j] = MFMA16(af[i], bfr[j], acc[i][j]);
    }
  }

#pragma unroll
  for (int i = 0; i < IM; ++i)
#pragma unroll
    for (int j = 0; j < JN; ++j) {
      int col = n0 + wn + j * 16 + m16;
      float bv = (MODE == 0) ? 0.0f : bias[col];
#pragma unroll
      for (int r = 0; r < 4; ++r) {
        int row = m0 + wm + i * 16 + quad * 4 + r;
        float v = acc[i][j][r];
        if (MODE != 0) v += bv;
        if (MODE == 1) v = v > 0.0f ? v : 0.0f;
        if (MODE == 2) {
          v += resid[(size_t)row * ldc + col];
          outF[(size_t)row * ldc + col] = v;
        } else {
          outB[(size_t)row * ldc + col] = f2b(v);
        }
      }
    }
}

// ---------------------------------------------------------------- attention v4

// Causal flash attention. Grid (32 qblocks reversed, 16 heads, 2 batch), 256 thr.
// 4 waves x 16 q-rows = 64 q/block. Double-buffered 64-key LDS tiles with
// register prefetch: one barrier per iteration, global latency hidden behind
// compute. S^T = K*Q^T (bf16); P^T packed in-register to f16 B-frags;
// O^T = V^T*P^T (f16). Scores pre-scaled by 0.125*log2e -> p = exp2(s - m).
__global__ __launch_bounds__(256) void attn_kernel(const u16* __restrict__ qkv,
                                                   u16* __restrict__ attn_out) {
  int qblock = 31 - blockIdx.x;  // big blocks dispatch first
  int h = blockIdx.y, b = blockIdx.z;
  int t = threadIdx.x, lane = t & 63, w = t >> 6;
  int m16 = lane & 15, quad = lane >> 4;
  const int ldq = 3072;
  int qb0 = qblock * 64;
  int wq0 = qb0 + w * 16;
  int wq_max = wq0 + 15;

  __shared__ u16 Ks[2][64 * 72];  // [key][d] bf16
  __shared__ u16 Vt[2][64 * 72];  // [d][key] f16

  // Q fragment (B-operand of S^T MFMA); scale+log2e folded into wq pack
  bf16x8 qa0, qa1;
  {
    const u16* qp = qkv + (size_t)(b * 2048 + wq0 + m16) * ldq + h * 64;
    qa0 = *(const bf16x8*)&qp[quad * 8];
    qa1 = *(const bf16x8*)&qp[32 + quad * 8];
  }

  f32x4 oT[4] = {};   // O^T tiles [ds]: row=d-local(quad*4+r), col=q(m16)
  f32x4 lacc = {};    // per-lane partial row sums (quad-partial)
  float mrun = -1e30f;

  int iters = qblock + 1;
  int srow = t >> 2;      // staging key row 0..63
  int sc = (t & 3) * 16;  // staging d-base
  int rr = srow & 15;
  int odd = rr & 1, r2 = rr & 2;

  uint4 ka, kb, va, vb;  // prefetch registers

#define GLOB_LOAD(IT)                                                                   \
  {                                                                                     \
    const u16* kg = qkv + (size_t)(b * 2048 + (IT) * 64 + srow) * ldq + 1024 + h * 64 + sc; \
    ka = *(const uint4*)&kg[0];                                                         \
    kb = *(const uint4*)&kg[8];                                                         \
    va = *(const uint4*)&kg[1024];                                                      \
    vb = *(const uint4*)&kg[1032];                                                      \
  }

#define STAGE(BUFI)                                                                     \
  {                                                                                     \
    *(uint4*)&Ks[BUFI][srow * 72 + sc] = ka;                                            \
    *(uint4*)&Ks[BUFI][srow * 72 + sc + 8] = kb;                                        \
    uint4 mine = odd ? vb : va;                                                         \
    uint4 sendv = odd ? va : vb;                                                        \
    u32 tx = __shfl_xor(sendv.x, 4), ty = __shfl_xor(sendv.y, 4);                       \
    u32 tz = __shfl_xor(sendv.z, 4), tw = __shfl_xor(sendv.w, 4);                       \
    u32 ke0 = odd ? tx : mine.x, ko0 = odd ? mine.x : tx;                               \
    u32 ke1 = odd ? ty : mine.y, ko1 = odd ? mine.y : ty;                               \
    u32 ke2 = odd ? tz : mine.z, ko2 = odd ? mine.z : tz;                               \
    u32 ke3 = odd ? tw : mine.w, ko3 = odd ? mine.w : tw;                               \
    u32 p0 = __builtin_amdgcn_perm(ko0, ke0, 0x05040100u);                              \
    u32 p1 = __builtin_amdgcn_perm(ko0, ke0, 0x07060302u);                              \
    u32 p2 = __builtin_amdgcn_perm(ko1, ke1, 0x05040100u);                              \
    u32 p3 = __builtin_amdgcn_perm(ko1, ke1, 0x07060302u);                              \
    u32 p4 = __builtin_amdgcn_perm(ko2, ke2, 0x05040100u);                              \
    u32 p5 = __builtin_amdgcn_perm(ko2, ke2, 0x07060302u);                              \
    u32 p6 = __builtin_amdgcn_perm(ko3, ke3, 0x05040100u);                              \
    u32 p7 = __builtin_amdgcn_perm(ko3, ke3, 0x07060302u);                              \
    u32 q0 = __shfl_xor(r2 ? p0 : p4, 8);                                               \
    u32 q1 = __shfl_xor(r2 ? p1 : p5, 8);                                               \
    u32 q2 = __shfl_xor(r2 ? p2 : p6, 8);                                               \
    u32 q3 = __shfl_xor(r2 ? p3 : p7, 8);                                               \
    int Df = sc + odd * 8 + (r2 ? 4 : 0);                                               \
    int key0 = srow & ~3;                                                               \
    u32x2 w0 = {bf2h2(r2 ? q0 : p0), bf2h2(r2 ? p4 : q0)};                              \
    u32x2 w1 = {bf2h2(r2 ? q1 : p1), bf2h2(r2 ? p5 : q1)};                              \
    u32x2 w2 = {bf2h2(r2 ? q2 : p2), bf2h2(r2 ? p6 : q2)};                              \
    u32x2 w3 = {bf2h2(r2 ? q3 : p3), bf2h2(r2 ? p7 : q3)};                              \
    *(u32x2*)&Vt[BUFI][(Df + 0) * 72 + key0] = w0;                                      \
    *(u32x2*)&Vt[BUFI][(Df + 1) * 72 + key0] = w1;                                      \
    *(u32x2*)&Vt[BUFI][(Df + 2) * 72 + key0] = w2;                                      \
    *(u32x2*)&Vt[BUFI][(Df + 3) * 72 + key0] = w3;                                      \
  }

  GLOB_LOAD(0);
  STAGE(0);
  __syncthreads();

  for (int it = 0; it < iters; ++it) {
    int t0 = it * 64;
    int cur = it & 1;
    bool notlast = (it + 1 < iters);
    if (notlast) GLOB_LOAD(it + 1);  // issue early; used in STAGE below

    if (t0 <= wq_max) {
      // ---- S^T = K Q^T : rows key, cols q ----
      f32x4 sv[4];
#pragma unroll
      for (int ts = 0; ts < 4; ++ts) {
        bf16x8 ka0 = *(const bf16x8*)&Ks[cur][(ts * 16 + m16) * 72 + quad * 8];
        bf16x8 ka1 = *(const bf16x8*)&Ks[cur][(ts * 16 + m16) * 72 + 32 + quad * 8];
        f32x4 a = {};
        a = MFMA16(ka0, qa0, a);
        a = MFMA16(ka1, qa1, a);
        sv[ts] = a;
      }
      // ---- causal mask (keys are rows) ----
      if (t0 + 63 > wq0) {
#pragma unroll
        for (int ts = 0; ts < 4; ++ts)
#pragma unroll
          for (int r = 0; r < 4; ++r) {
            int key = t0 + ts * 16 + quad * 4 + r;
            if (key > wq0 + m16) sv[ts][r] = -3e38f;
          }
      }
      // ---- wave-shared max ----
      f32x4 m4 = sv[0];
#pragma unroll
      for (int ts = 1; ts < 4; ++ts)
#pragma unroll
        for (int r = 0; r < 4; ++r) m4[r] = fmaxf(m4[r], sv[ts][r]);
      float mx = fmaxf(fmaxf(m4[0], m4[1]), fmaxf(m4[2], m4[3]));
#pragma unroll
      for (int d = 1; d < 64; d <<= 1) mx = fmaxf(mx, __shfl_xor(mx, d));
      if (mx > mrun) {  // wave-uniform rescale
        float alpha = exp2f(mrun - mx);
        lacc *= alpha;
#pragma unroll
        for (int ds = 0; ds < 4; ++ds) oT[ds] *= alpha;
        mrun = mx;
      }
      // ---- p = exp2(s-m); accumulate l; pack P^T f16 frags in-register ----
      f16x4 pf[4];
#pragma unroll
      for (int ts = 0; ts < 4; ++ts) {
        float p0 = exp2f(sv[ts][0] - mrun);
        float p1 = exp2f(sv[ts][1] - mrun);
        float p2 = exp2f(sv[ts][2] - mrun);
        float p3 = exp2f(sv[ts][3] - mrun);
        lacc[0] += p0;
        lacc[1] += p1;
        lacc[2] += p2;
        lacc[3] += p3;
        pf[ts] = pack4h(p0, p1, p2, p3);
      }
      // ---- O^T += V^T P^T ----
#pragma unroll
      for (int ts = 0; ts < 4; ++ts)
#pragma unroll
        for (int ds = 0; ds < 4; ++ds) {
          f16x4 av = __builtin_bit_cast(
              f16x4, *(const u32x2*)&Vt[cur][(ds * 16 + m16) * 72 + ts * 16 + quad * 4]);
          oT[ds] = MFMAH(av, pf[ts], oT[ds]);
        }
    }

    if (notlast) STAGE(!cur);  // other buffer: no WAR with this iter's reads
    __syncthreads();
  }

  // ---- epilogue: reduce l across quads, normalize, store bf16 ----
  float ls = lacc[0] + lacc[1] + lacc[2] + lacc[3];
  ls += __shfl_xor(ls, 16);
  ls += __shfl_xor(ls, 32);
  float rl = 1.0f / ls;
  int q = wq0 + m16;
#pragma unroll
  for (int ds = 0; ds < 4; ++ds) {
    f32x4 o = oT[ds];
    u32x2 ov = {(u32)f2b(o[0] * rl) | ((u32)f2b(o[1] * rl) << 16),
                (u32)f2b(o[2] * rl) | ((u32)f2b(o[3] * rl) << 16)};
    *(u32x2*)&attn_out[(size_t)(b * 2048 + q) * 1024 + h * 64 + ds * 16 + quad * 4] = ov;
  }
#undef GLOB_LOAD
#undef STAGE
}

// ---------------------------------------------------------------- layernorm

__global__ __launch_bounds__(256) void ln_kernel(const float* __restrict__ in,
                                                 const float* __restrict__ g,
                                                 const float* __restrict__ be,
                                                 float* __restrict__ outF,
                                                 u16* __restrict__ outB) {
  int row = blockIdx.x;
  int t = threadIdx.x;
  const float* p = in + (size_t)row * 1024 + t * 4;
  float4 v = *(const float4*)p;
  float s = v.x + v.y + v.z + v.w;
  float sq = v.x * v.x + v.y * v.y + v.z * v.z + v.w * v.w;
#pragma unroll
  for (int d = 1; d < 64; d <<= 1) {
    s += __shfl_xor(s, d);
    sq += __shfl_xor(sq, d);
  }
  __shared__ float red[8];
  int lane = t & 63, wid = t >> 6;
  if (lane == 0) {
    red[wid] = s;
    red[4 + wid] = sq;
  }
  __syncthreads();
  s = red[0] + red[1] + red[2] + red[3];
  sq = red[4] + red[5] + red[6] + red[7];
  float mu = s * (1.0f / 1024.0f);
  float var = sq * (1.0f / 1024.0f) - mu * mu;
  float rstd = rsqrtf(var + 1e-5f);
  float4 gv = *(const float4*)(g + t * 4);
  float4 bv = *(const float4*)(be + t * 4);
  float o0 = (v.x - mu) * rstd * gv.x + bv.x;
  float o1 = (v.y - mu) * rstd * gv.y + bv.y;
  float o2 = (v.z - mu) * rstd * gv.z + bv.z;
  float o3 = (v.w - mu) * rstd * gv.w + bv.w;
  size_t o = (size_t)row * 1024 + t * 4;
  if (outF) {
    float4 ov = {o0, o1, o2, o3};
    *(float4*)(outF + o) = ov;
  }
  if (outB) {
    outB[o + 0] = f2b(o0);
    outB[o + 1] = f2b(o1);
    outB[o + 2] = f2b(o2);
    outB[o + 3] = f2b(o3);
  }
}

// ---------------------------------------------------------------- launch

extern "C" void kernel_launch(void* const* d_in, const int* in_sizes, int n_in,
                              void* d_out, int out_size, void* d_ws, size_t ws_size,
                              hipStream_t stream) {
  const float* x = (const float*)d_in[0];
  const float* wq = (const float*)d_in[1];
  const float* wk = (const float*)d_in[2];
  const float* wv = (const float*)d_in[3];
  const float* w_proj = (const float*)d_in[4];
  const float* b_proj = (const float*)d_in[5];
  const float* w1 = (const float*)d_in[6];
  const float* b1 = (const float*)d_in[7];
  const float* w2 = (const float*)d_in[8];
  const float* b2 = (const float*)d_in[9];
  const float* g1 = (const float*)d_in[10];
  const float* be1 = (const float*)d_in[11];
  const float* g2 = (const float*)d_in[12];
  const float* be2 = (const float*)d_in[13];
  float* out = (float*)d_out;

  const int M = 4096;  // B*S
  char* w = (char*)d_ws;
  u16* Xbf = (u16*)w;        w += (size_t)M * 1024 * 2;
  u16* WqkvT = (u16*)w;      w += (size_t)3072 * 1024 * 2;
  u16* WprojT = (u16*)w;     w += (size_t)1024 * 1024 * 2;
  u16* W1T = (u16*)w;        w += (size_t)4096 * 1024 * 2;
  u16* W2T = (u16*)w;        w += (size_t)1024 * 4096 * 2;
  u16* QKV = (u16*)w;        w += (size_t)M * 3072 * 2;
  u16* Attn = (u16*)w;       w += (size_t)M * 1024 * 2;
  float* X1f = (float*)w;    w += (size_t)M * 1024 * 4;
  u16* X1b = (u16*)w;        w += (size_t)M * 1024 * 2;
  u16* Hbuf = QKV;  // aliases dead QKV+Attn region after proj GEMM

  // 1. pack
  castx_kernel<<<M * 1024 / 1024, 256, 0, stream>>>(x, Xbf);
  tcast_qkv_kernel<<<dim3(2, 32, 48), dim3(32, 8), 0, stream>>>(wq, wk, wv, WqkvT);
  tcast_kernel<<<dim3(32, 32), dim3(32, 8), 0, stream>>>(w_proj, WprojT, 1024, 1024);
  tcast_kernel<<<dim3(128, 32), dim3(32, 8), 0, stream>>>(w1, W1T, 1024, 4096);
  tcast_kernel<<<dim3(32, 128), dim3(32, 8), 0, stream>>>(w2, W2T, 4096, 1024);

  // 2. QKV projection: grid 24x32 = 768 blocks
  gemm_bf16<0, 128><<<dim3(3072 / 128, M / 128), 256, 0, stream>>>(
      Xbf, WqkvT, M, 3072, 1024, nullptr, nullptr, QKV, nullptr, 3072);

  // 3. causal flash attention: 1024 blocks, LPT order
  attn_kernel<<<dim3(32, 16, 2), 256, 0, stream>>>(QKV, Attn);

  // 4. proj + bias + residual(x) -> d_out fp32: BN=64, 16x32 = 512 blocks
  gemm_bf16<2, 64><<<dim3(1024 / 64, M / 128), 256, 0, stream>>>(
      Attn, WprojT, M, 1024, 1024, b_proj, x, nullptr, out, 1024);

  // 5. LN1
  ln_kernel<<<M, 256, 0, stream>>>(out, g1, be1, X1f, X1b);

  // 6. MLP up: 32x32 = 1024 blocks
  gemm_bf16<1, 128><<<dim3(4096 / 128, M / 128), 256, 0, stream>>>(
      X1b, W1T, M, 4096, 1024, b1, nullptr, Hbuf, nullptr, 4096);

  // 7. MLP down + residual: BN=64, 512 blocks
  gemm_bf16<2, 64><<<dim3(1024 / 64, M / 128), 256, 0, stream>>>(
      Hbuf, W2T, M, 1024, 4096, b2, X1f, nullptr, out, 1024);

  // 8. LN2 in-place
  ln_kernel<<<M, 256, 0, stream>>>(out, g2, be2, out, nullptr);
}

// Round 6
// 357.451 us; speedup vs baseline: 1.6179x; 1.2273x over previous
//
#include <hip/hip_runtime.h>

// Transformer block on MI355X. bf16 MFMA for GEMMs/QK^T, fp16 MFMA for PV, fp32 stats.
// GEMM: C[M,N] = A[M,K] (row-major bf16) x Bt[N,K] (row-major bf16 = B^T).
// MFMA 16x16x32 bf16 frags: A/B [idx=lane&15][k=quad*8+j]; C/D col=lane&15, row=quad*4+reg.
// MFMA 16x16x16 f16 frags:  A/B [idx=lane&15][k=quad*4+j]; C/D same 16x16 layout.
// Attention identity: S^T C-layout == 16x16x16 B-operand layout, so P^T goes from
// the QK^T MFMA output straight into the PV MFMA with no LDS round-trip.
// V is produced TRANSPOSED as f16 by the QKV GEMM epilogue (Vtg[b][h][d][token]),
// so attention staging is pure async DMA (global_load_lds) — no transpose VALU.

typedef unsigned short u16;
typedef unsigned int u32;
typedef __attribute__((ext_vector_type(8))) short bf16x8;
typedef __attribute__((ext_vector_type(4))) float f32x4;
typedef __attribute__((ext_vector_type(2))) u32 u32x2;
typedef __attribute__((ext_vector_type(4))) _Float16 f16x4;

#define MFMA16(a, b, c) __builtin_amdgcn_mfma_f32_16x16x32_bf16(a, b, c, 0, 0, 0)
#define MFMAH(a, b, c) __builtin_amdgcn_mfma_f32_16x16x16f16(a, b, c, 0, 0, 0)

__device__ __forceinline__ u16 f2b(float f) {
  unsigned int u = __builtin_bit_cast(unsigned int, f);
  u = (u + 0x7fffu + ((u >> 16) & 1u)) >> 16;
  return (u16)u;
}

// async 16B/lane global->LDS; LDS dst = wave-uniform base + lane*16.
__device__ __forceinline__ void gload_lds16(const u16* g, u16* l) {
  __builtin_amdgcn_global_load_lds((const __attribute__((address_space(1))) void*)g,
                                   (__attribute__((address_space(3))) void*)l, 16, 0, 0);
}

__device__ __forceinline__ u32 pkrtz(float lo, float hi) {
  return __builtin_bit_cast(u32, __builtin_amdgcn_cvt_pkrtz(lo, hi));
}

__device__ __forceinline__ f16x4 pack4h(float a, float b, float c, float d) {
  u32x2 r = {pkrtz(a, b), pkrtz(c, d)};
  return __builtin_bit_cast(f16x4, r);
}

// ---------------------------------------------------------------- pack kernels

__global__ __launch_bounds__(256) void castx_kernel(const float* __restrict__ src,
                                                    u16* __restrict__ dst) {
  int i = (blockIdx.x * 256 + threadIdx.x) * 4;
  float4 v = *(const float4*)(src + i);
  dst[i + 0] = f2b(v.x);
  dst[i + 1] = f2b(v.y);
  dst[i + 2] = f2b(v.z);
  dst[i + 3] = f2b(v.w);
}

// tiled transpose+cast: dst[c*R + r] = bf16(src[r*C + c])
__global__ __launch_bounds__(256) void tcast_kernel(const float* __restrict__ src,
                                                    u16* __restrict__ dst, int R, int C) {
  __shared__ float tile[32][33];
  int tx = threadIdx.x, ty = threadIdx.y;
  int r0 = blockIdx.y * 32, c0 = blockIdx.x * 32;
#pragma unroll
  for (int i = 0; i < 4; ++i)
    tile[ty + i * 8][tx] = src[(size_t)(r0 + ty + i * 8) * C + c0 + tx];
  __syncthreads();
#pragma unroll
  for (int i = 0; i < 4; ++i)
    dst[(size_t)(c0 + ty + i * 8) * R + r0 + tx] = f2b(tile[tx][ty + i * 8]);
}

// per-(proj,head) transpose of [1024 d][64 k] into WqkvT[n=p*1024+h*64+k][d].
// q gets (1/sqrt(64))*log2(e) folded in (attn uses exp2).
__global__ __launch_bounds__(256) void tcast_qkv_kernel(const float* __restrict__ wq,
                                                        const float* __restrict__ wk,
                                                        const float* __restrict__ wv,
                                                        u16* __restrict__ dst) {
  __shared__ float tile[32][33];
  int tx = threadIdx.x, ty = threadIdx.y;
  int z = blockIdx.z;
  int p = z >> 4, h = z & 15;
  const float* src = (p == 0 ? wq : (p == 1 ? wk : wv)) + (size_t)h * 1024 * 64;
  float scale = (p == 0) ? 0.1803368801f : 1.0f;  // 0.125 * log2(e)
  u16* dbase = dst + (size_t)(p * 1024 + h * 64) * 1024;
  int r0 = blockIdx.y * 32, c0 = blockIdx.x * 32;
#pragma unroll
  for (int i = 0; i < 4; ++i)
    tile[ty + i * 8][tx] = src[(size_t)(r0 + ty + i * 8) * 64 + c0 + tx];
  __syncthreads();
#pragma unroll
  for (int i = 0; i < 4; ++i)
    dbase[(size_t)(c0 + ty + i * 8) * 1024 + r0 + tx] = f2b(tile[tx][ty + i * 8] * scale);
}

// ---------------------------------------------------------------- GEMM v2
// BK=64; LDS dense [rows][64] staged via global_load_lds with 16B-chunk XOR
// swizzle (chunk c of row r lives at slot c^(r&7)) -> b128 frag reads are
// 2-addr/bank (free). BN=128: wave grid 2x2 (64x64/wave). BN=64: 4x1 (32x64).
// MODE 0: C bf16 -> outB | 1: relu(C+bias) bf16 | 2: C+bias+resid fp32
// MODE 3: QKV fused: n0<2048 -> bf16 natural (ldc) | n0>=2048 -> V^T f16 to vtg

template <int MODE, int BN>
__global__ __launch_bounds__(256) void gemm_bf16(const u16* __restrict__ A,
                                                 const u16* __restrict__ Bt, int M, int N,
                                                 int K, const float* __restrict__ bias,
                                                 const float* __restrict__ resid,
                                                 u16* __restrict__ outB,
                                                 float* __restrict__ outF, int ldc,
                                                 u16* __restrict__ vtg) {
  constexpr int BM = 128, BK = 64;
  constexpr int IM = (BN == 128) ? 4 : 2;  // 16-row tiles per wave
  constexpr int JN = 4;                    // 16-col tiles per wave
  __shared__ u16 As[BM * BK];
  __shared__ u16 Bs[BN * BK];
  int t = threadIdx.x;
  int m0 = blockIdx.y * BM, n0 = blockIdx.x * BN;
  int lane = t & 63, wid = t >> 6;
  int wm = (BN == 128) ? (wid >> 1) * 64 : wid * 32;
  int wn = (BN == 128) ? (wid & 1) * 64 : 0;
  int m16 = lane & 15, quad = lane >> 4;
  int sw = m16 & 7;  // read-side swizzle key (row&7 == m16&7 for 16-aligned tiles)

  f32x4 acc[IM][JN] = {};

  for (int k0 = 0; k0 < K; k0 += BK) {
    __syncthreads();
#pragma unroll
    for (int i = 0; i < 4; ++i) {  // A: 1024 slots
      int S = i * 256 + t;
      int row = S >> 3, c = S & 7;
      gload_lds16(&A[(size_t)(m0 + row) * K + k0 + (c ^ (row & 7)) * 8],
                  &As[(i * 256 + wid * 64) * 8]);
    }
#pragma unroll
    for (int i = 0; i < BN / 32; ++i) {  // B: BN*8 slots
      int S = i * 256 + t;
      int row = S >> 3, c = S & 7;
      gload_lds16(&Bt[(size_t)(n0 + row) * K + k0 + (c ^ (row & 7)) * 8],
                  &Bs[(i * 256 + wid * 64) * 8]);
    }
    __syncthreads();
#pragma unroll
    for (int kk = 0; kk < 2; ++kk) {
      bf16x8 af[IM], bfr[JN];
      int slot = (kk * 4 + quad) ^ sw;
#pragma unroll
      for (int i = 0; i < IM; ++i)
        af[i] = *(const bf16x8*)&As[(wm + i * 16 + m16) * BK + slot * 8];
#pragma unroll
      for (int j = 0; j < JN; ++j)
        bfr[j] = *(const bf16x8*)&Bs[(wn + j * 16 + m16) * BK + slot * 8];
#pragma unroll
      for (int i = 0; i < IM; ++i)
#pragma unroll
        for (int j = 0; j < JN; ++j) acc[i][j] = MFMA16(af[i], bfr[j], acc[i][j]);
    }
  }

  if (MODE == 3 && n0 >= 2048) {
    // V region: write transposed f16 -> vtg[b][h][d][token]
#pragma unroll
    for (int i = 0; i < IM; ++i)
#pragma unroll
      for (int j = 0; j < JN; ++j) {
        int dg = n0 + wn + j * 16 + m16 - 2048;
        int hh = dg >> 6, dd = dg & 63;
        int token = m0 + wm + i * 16 + quad * 4;
        int bb = token >> 11, tt = token & 2047;
        u32x2 pv = {pkrtz(acc[i][j][0], acc[i][j][1]),
                    pkrtz(acc[i][j][2], acc[i][j][3])};
        *(u32x2*)&vtg[(((size_t)bb * 16 + hh) * 64 + dd) * 2048 + tt] = pv;
      }
    return;
  }

#pragma unroll
  for (int i = 0; i < IM; ++i)
#pragma unroll
    for (int j = 0; j < JN; ++j) {
      int col = n0 + wn + j * 16 + m16;
      float bv = (MODE == 0 || MODE == 3) ? 0.0f : bias[col];
#pragma unroll
      for (int r = 0; r < 4; ++r) {
        int row = m0 + wm + i * 16 + quad * 4 + r;
        float v = acc[i][j][r];
        if (MODE == 1 || MODE == 2) v += bv;
        if (MODE == 1) v = v > 0.0f ? v : 0.0f;
        if (MODE == 2) {
          v += resid[(size_t)row * ldc + col];
          outF[(size_t)row * ldc + col] = v;
        } else {
          outB[(size_t)row * ldc + col] = f2b(v);
        }
      }
    }
}

// ---------------------------------------------------------------- attention v5

// Causal flash attention. Grid 512 blocks (zigzag LPT: block c and c+256 land on
// the same CU and their iteration counts sum to a constant). 4 waves x 32 q = 128
// q/block (max K/V reuse). K (bf16, natural) and V^T (f16, from Vtg) staged via
// async global_load_lds with 16B-chunk XOR swizzle: zero staging VALU, conflict-
// free reads. Double-buffered, one barrier/iter. S^T = K*Q^T; P^T packed
// in-register to f16 B-frags; O^T = V^T*P^T. Scores pre-scaled by 0.125*log2e.
__global__ __launch_bounds__(256) void attn_kernel(const u16* __restrict__ qk,
                                                   const u16* __restrict__ vtg,
                                                   u16* __restrict__ attn_out) {
  int bid = blockIdx.x;
  int r = bid < 256 ? bid : 767 - bid;  // zigzag LPT rank
  int qblock = 15 - (r >> 5);
  int pair = r & 31;
  int h = pair & 15, b = pair >> 4;
  int t = threadIdx.x, lane = t & 63, w = t >> 6;
  int m16 = lane & 15, quad = lane >> 4;
  int qb0 = qblock * 128;
  int wq0 = qb0 + w * 32;

  __shared__ u16 Ks[2][64 * 64];  // [key][d] bf16, chunk-swizzled
  __shared__ u16 Vs[2][64 * 64];  // [d][key] f16, chunk-swizzled

  // Q fragments (B-operand of S^T MFMA); scale+log2e folded into wq pack
  bf16x8 qa[2][2];
#pragma unroll
  for (int qs = 0; qs < 2; ++qs) {
    const u16* qp = qk + (size_t)(b * 2048 + wq0 + qs * 16 + m16) * 2048 + h * 64;
    qa[qs][0] = *(const bf16x8*)&qp[quad * 8];
    qa[qs][1] = *(const bf16x8*)&qp[32 + quad * 8];
  }

  f32x4 oT[2][4] = {};  // O^T tiles [qs][ds]: row=d-local(quad*4+r), col=q(m16)
  f32x4 lacc[2] = {};   // per-lane partial row sums (quad-partial)
  float mrun = -1e30f;

  int iters = 2 * qblock + 2;
  int row0 = t >> 3, c0 = t & 7;  // staging slot S=t: row, chunk
  int row1 = 32 + row0;           // staging slot S=256+t
  const u16* kbase = qk + (size_t)(b * 2048) * 2048 + 1024 + h * 64;
  const u16* vbase = vtg + ((size_t)(b * 16 + h) * 64) * 2048;
  int sw = m16 & 7;

#define STAGE_ASYNC(IT, BUF)                                                          \
  {                                                                                   \
    int tt0 = (IT) * 64;                                                              \
    gload_lds16(&kbase[(size_t)(tt0 + row0) * 2048 + (c0 ^ (row0 & 7)) * 8],          \
                &Ks[BUF][(w * 64) * 8]);                                              \
    gload_lds16(&kbase[(size_t)(tt0 + row1) * 2048 + (c0 ^ (row1 & 7)) * 8],          \
                &Ks[BUF][(256 + w * 64) * 8]);                                        \
    gload_lds16(&vbase[(size_t)row0 * 2048 + tt0 + (c0 ^ (row0 & 7)) * 8],            \
                &Vs[BUF][(w * 64) * 8]);                                              \
    gload_lds16(&vbase[(size_t)row1 * 2048 + tt0 + (c0 ^ (row1 & 7)) * 8],            \
                &Vs[BUF][(256 + w * 64) * 8]);                                        \
  }

  STAGE_ASYNC(0, 0);
  __syncthreads();

  for (int it = 0; it < iters; ++it) {
    int t0 = it * 64;
    int cur = it & 1;
    if (it + 1 < iters) STAGE_ASYNC(it + 1, !cur);  // async into other buffer

    if (t0 <= wq0 + 31) {
      // ---- S^T = K Q^T : rows key, cols q ----
      f32x4 sv[2][4];
#pragma unroll
      for (int ts = 0; ts < 4; ++ts) {
        bf16x8 ka0 = *(const bf16x8*)&Ks[cur][(ts * 16 + m16) * 64 + (quad ^ sw) * 8];
        bf16x8 ka1 =
            *(const bf16x8*)&Ks[cur][(ts * 16 + m16) * 64 + ((4 + quad) ^ sw) * 8];
#pragma unroll
        for (int qs = 0; qs < 2; ++qs) {
          f32x4 a = {};
          a = MFMA16(ka0, qa[qs][0], a);
          a = MFMA16(ka1, qa[qs][1], a);
          sv[qs][ts] = a;
        }
      }
      // ---- causal mask (keys are rows) ----
      if (t0 + 63 > wq0) {
#pragma unroll
        for (int qs = 0; qs < 2; ++qs)
#pragma unroll
          for (int ts = 0; ts < 4; ++ts)
#pragma unroll
            for (int rr = 0; rr < 4; ++rr) {
              int key = t0 + ts * 16 + quad * 4 + rr;
              if (key > wq0 + qs * 16 + m16) sv[qs][ts][rr] = -3e38f;
            }
      }
      // ---- wave-shared max ----
      f32x4 m4 = sv[0][0];
#pragma unroll
      for (int qs = 0; qs < 2; ++qs)
#pragma unroll
        for (int ts = 0; ts < 4; ++ts) {
          if (qs == 0 && ts == 0) continue;
#pragma unroll
          for (int rr = 0; rr < 4; ++rr) m4[rr] = fmaxf(m4[rr], sv[qs][ts][rr]);
        }
      float mx = fmaxf(fmaxf(m4[0], m4[1]), fmaxf(m4[2], m4[3]));
#pragma unroll
      for (int d = 1; d < 64; d <<= 1) mx = fmaxf(mx, __shfl_xor(mx, d));
      if (mx > mrun) {  // wave-uniform rescale
        float alpha = exp2f(mrun - mx);
#pragma unroll
        for (int qs = 0; qs < 2; ++qs) {
          lacc[qs] *= alpha;
#pragma unroll
          for (int ds = 0; ds < 4; ++ds) oT[qs][ds] *= alpha;
        }
        mrun = mx;
      }
      // ---- p = exp2(s-m); accumulate l; pack P^T f16 B-frags in-register ----
      f16x4 pf[2][4];
#pragma unroll
      for (int qs = 0; qs < 2; ++qs)
#pragma unroll
        for (int ts = 0; ts < 4; ++ts) {
          float p0 = exp2f(sv[qs][ts][0] - mrun);
          float p1 = exp2f(sv[qs][ts][1] - mrun);
          float p2 = exp2f(sv[qs][ts][2] - mrun);
          float p3 = exp2f(sv[qs][ts][3] - mrun);
          lacc[qs][0] += p0;
          lacc[qs][1] += p1;
          lacc[qs][2] += p2;
          lacc[qs][3] += p3;
          pf[qs][ts] = pack4h(p0, p1, p2, p3);
        }
      // ---- O^T += V^T P^T ----
#pragma unroll
      for (int ts = 0; ts < 4; ++ts)
#pragma unroll
        for (int ds = 0; ds < 4; ++ds) {
          f16x4 av = __builtin_bit_cast(
              f16x4, *(const u32x2*)&Vs[cur][(ds * 16 + m16) * 64 +
                                             (((ts * 2 + (quad >> 1)) ^ sw) * 8) +
                                             (quad & 1) * 4]);
          oT[0][ds] = MFMAH(av, pf[0][ts], oT[0][ds]);
          oT[1][ds] = MFMAH(av, pf[1][ts], oT[1][ds]);
        }
    }
    __syncthreads();  // drains next tile's DMA; protects buffer reuse
  }
#undef STAGE_ASYNC

  // ---- epilogue: reduce l across quads, normalize, store bf16 ----
#pragma unroll
  for (int qs = 0; qs < 2; ++qs) {
    float ls = lacc[qs][0] + lacc[qs][1] + lacc[qs][2] + lacc[qs][3];
    ls += __shfl_xor(ls, 16);
    ls += __shfl_xor(ls, 32);
    float rl = 1.0f / ls;
    int q = wq0 + qs * 16 + m16;
#pragma unroll
    for (int ds = 0; ds < 4; ++ds) {
      f32x4 o = oT[qs][ds];
      u32x2 ov = {(u32)f2b(o[0] * rl) | ((u32)f2b(o[1] * rl) << 16),
                  (u32)f2b(o[2] * rl) | ((u32)f2b(o[3] * rl) << 16)};
      *(u32x2*)&attn_out[(size_t)(b * 2048 + q) * 1024 + h * 64 + ds * 16 + quad * 4] =
          ov;
    }
  }
}

// ---------------------------------------------------------------- layernorm

__global__ __launch_bounds__(256) void ln_kernel(const float* __restrict__ in,
                                                 const float* __restrict__ g,
                                                 const float* __restrict__ be,
                                                 float* __restrict__ outF,
                                                 u16* __restrict__ outB) {
  int row = blockIdx.x;
  int t = threadIdx.x;
  const float* p = in + (size_t)row * 1024 + t * 4;
  float4 v = *(const float4*)p;
  float s = v.x + v.y + v.z + v.w;
  float sq = v.x * v.x + v.y * v.y + v.z * v.z + v.w * v.w;
#pragma unroll
  for (int d = 1; d < 64; d <<= 1) {
    s += __shfl_xor(s, d);
    sq += __shfl_xor(sq, d);
  }
  __shared__ float red[8];
  int lane = t & 63, wid = t >> 6;
  if (lane == 0) {
    red[wid] = s;
    red[4 + wid] = sq;
  }
  __syncthreads();
  s = red[0] + red[1] + red[2] + red[3];
  sq = red[4] + red[5] + red[6] + red[7];
  float mu = s * (1.0f / 1024.0f);
  float var = sq * (1.0f / 1024.0f) - mu * mu;
  float rstd = rsqrtf(var + 1e-5f);
  float4 gv = *(const float4*)(g + t * 4);
  float4 bv = *(const float4*)(be + t * 4);
  float o0 = (v.x - mu) * rstd * gv.x + bv.x;
  float o1 = (v.y - mu) * rstd * gv.y + bv.y;
  float o2 = (v.z - mu) * rstd * gv.z + bv.z;
  float o3 = (v.w - mu) * rstd * gv.w + bv.w;
  size_t o = (size_t)row * 1024 + t * 4;
  if (outF) {
    float4 ov = {o0, o1, o2, o3};
    *(float4*)(outF + o) = ov;
  }
  if (outB) {
    outB[o + 0] = f2b(o0);
    outB[o + 1] = f2b(o1);
    outB[o + 2] = f2b(o2);
    outB[o + 3] = f2b(o3);
  }
}

// ---------------------------------------------------------------- launch

extern "C" void kernel_launch(void* const* d_in, const int* in_sizes, int n_in,
                              void* d_out, int out_size, void* d_ws, size_t ws_size,
                              hipStream_t stream) {
  const float* x = (const float*)d_in[0];
  const float* wq = (const float*)d_in[1];
  const float* wk = (const float*)d_in[2];
  const float* wv = (const float*)d_in[3];
  const float* w_proj = (const float*)d_in[4];
  const float* b_proj = (const float*)d_in[5];
  const float* w1 = (const float*)d_in[6];
  const float* b1 = (const float*)d_in[7];
  const float* w2 = (const float*)d_in[8];
  const float* b2 = (const float*)d_in[9];
  const float* g1 = (const float*)d_in[10];
  const float* be1 = (const float*)d_in[11];
  const float* g2 = (const float*)d_in[12];
  const float* be2 = (const float*)d_in[13];
  float* out = (float*)d_out;

  const int M = 4096;  // B*S
  char* w = (char*)d_ws;
  u16* Xbf = (u16*)w;        w += (size_t)M * 1024 * 2;       // 8 MB
  u16* WqkvT = (u16*)w;      w += (size_t)3072 * 1024 * 2;    // 6 MB
  u16* WprojT = (u16*)w;     w += (size_t)1024 * 1024 * 2;    // 2 MB
  u16* W1T = (u16*)w;        w += (size_t)4096 * 1024 * 2;    // 8 MB
  u16* W2T = (u16*)w;        w += (size_t)1024 * 4096 * 2;    // 8 MB
  u16* QK = (u16*)w;         w += (size_t)M * 2048 * 2;       // 16 MB  (contig w/ next 2)
  u16* Vtg = (u16*)w;        w += (size_t)2 * 16 * 64 * 2048 * 2;  // 8 MB
  u16* Attn = (u16*)w;       w += (size_t)M * 1024 * 2;       // 8 MB
  float* X1f = (float*)w;    w += (size_t)M * 1024 * 4;       // 16 MB
  u16* X1b = (u16*)w;        w += (size_t)M * 1024 * 2;       // 8 MB
  u16* Hbuf = QK;  // aliases dead QK+Vtg+Attn (32 MB) after proj GEMM

  // 1. pack
  castx_kernel<<<M * 1024 / 1024, 256, 0, stream>>>(x, Xbf);
  tcast_qkv_kernel<<<dim3(2, 32, 48), dim3(32, 8), 0, stream>>>(wq, wk, wv, WqkvT);
  tcast_kernel<<<dim3(32, 32), dim3(32, 8), 0, stream>>>(w_proj, WprojT, 1024, 1024);
  tcast_kernel<<<dim3(128, 32), dim3(32, 8), 0, stream>>>(w1, W1T, 1024, 4096);
  tcast_kernel<<<dim3(32, 128), dim3(32, 8), 0, stream>>>(w2, W2T, 4096, 1024);

  // 2. QKV projection: Q,K natural bf16 (ldc=2048) + V transposed f16
  gemm_bf16<3, 128><<<dim3(3072 / 128, M / 128), 256, 0, stream>>>(
      Xbf, WqkvT, M, 3072, 1024, nullptr, nullptr, QK, nullptr, 2048, Vtg);

  // 3. causal flash attention: 512 blocks, zigzag LPT
  attn_kernel<<<512, 256, 0, stream>>>(QK, Vtg, Attn);

  // 4. proj + bias + residual(x) -> d_out fp32: BN=64, 512 blocks
  gemm_bf16<2, 64><<<dim3(1024 / 64, M / 128), 256, 0, stream>>>(
      Attn, WprojT, M, 1024, 1024, b_proj, x, nullptr, out, 1024, nullptr);

  // 5. LN1
  ln_kernel<<<M, 256, 0, stream>>>(out, g1, be1, X1f, X1b);

  // 6. MLP up: 1024 blocks
  gemm_bf16<1, 128><<<dim3(4096 / 128, M / 128), 256, 0, stream>>>(
      X1b, W1T, M, 4096, 1024, b1, nullptr, Hbuf, nullptr, 4096, nullptr);

  // 7. MLP down + residual: BN=64, 512 blocks
  gemm_bf16<2, 64><<<dim3(1024 / 64, M / 128), 256, 0, stream>>>(
      Hbuf, W2T, M, 1024, 4096, b2, X1f, nullptr, out, 1024, nullptr);

  // 8. LN2 in-place
  ln_kernel<<<M, 256, 0, stream>>>(out, g2, be2, out, nullptr);
}